// Round 1
// baseline (8129.840 us; speedup 1.0000x reference)
//
#include <hip/hip_runtime.h>
#include <cstdint>
#include <cstddef>

#define NFEAT 128

// ---------------- preprocessing kernels ----------------

__global__ void zero_ints(int* __restrict__ p, int n) {
    int i = blockIdx.x * blockDim.x + threadIdx.x;
    if (i < n) p[i] = 0;
}

__global__ void degree_kernel(const int* __restrict__ src, const int* __restrict__ dst,
                              int ne, int* __restrict__ out_cnt, int* __restrict__ in_cnt) {
    int e = blockIdx.x * blockDim.x + threadIdx.x;
    if (e < ne) {
        atomicAdd(&out_cnt[src[e]], 1);
        atomicAdd(&in_cnt[dst[e]], 1);
    }
}

__global__ void norm_kernel(const int* __restrict__ out_cnt, const int* __restrict__ in_cnt,
                            float* __restrict__ norm_s, float* __restrict__ norm_d, int n) {
    int i = blockIdx.x * blockDim.x + threadIdx.x;
    if (i < n) {
        norm_s[i] = rsqrtf(fmaxf((float)out_cnt[i], 1.0f));
        norm_d[i] = rsqrtf(fmaxf((float)in_cnt[i], 1.0f));
    }
}

// Block-wise exclusive scan (Hillis-Steele), 1024 threads/block.
__global__ void scan_phase1(const int* __restrict__ cnt, int* __restrict__ excl,
                            int* __restrict__ bsums, int n) {
    __shared__ int tmp[1024];
    int tid = threadIdx.x;
    int gid = blockIdx.x * 1024 + tid;
    int v = (gid < n) ? cnt[gid] : 0;
    tmp[tid] = v;
    for (int off = 1; off < 1024; off <<= 1) {
        __syncthreads();
        int t = (tid >= off) ? tmp[tid - off] : 0;
        __syncthreads();
        tmp[tid] += t;
    }
    __syncthreads();
    if (gid < n) excl[gid] = tmp[tid] - v;
    if (tid == 0) bsums[blockIdx.x] = tmp[1023];
}

__global__ void scan_phase2(int* __restrict__ bsums, int nb) {
    __shared__ int tmp[1024];
    int tid = threadIdx.x;
    int v = (tid < nb) ? bsums[tid] : 0;
    tmp[tid] = v;
    for (int off = 1; off < 1024; off <<= 1) {
        __syncthreads();
        int t = (tid >= off) ? tmp[tid - off] : 0;
        __syncthreads();
        tmp[tid] += t;
    }
    __syncthreads();
    if (tid < nb) bsums[tid] = tmp[tid] - v;
}

__global__ void scan_phase3(int* __restrict__ row_ptr, const int* __restrict__ bsums,
                            int* __restrict__ cursor, int n, int ne) {
    int gid = blockIdx.x * 1024 + threadIdx.x;
    if (gid < n) {
        int r = row_ptr[gid] + bsums[blockIdx.x];
        row_ptr[gid] = r;
        cursor[gid] = r;
    }
    if (gid == 0) row_ptr[n] = ne;
}

__global__ void scatter_kernel(const int* __restrict__ src, const int* __restrict__ dst,
                               int ne, int* __restrict__ cursor, int* __restrict__ csr_src) {
    int e = blockIdx.x * blockDim.x + threadIdx.x;
    if (e < ne) {
        int d = dst[e];
        int p = atomicAdd(&cursor[d], 1);
        csr_src[p] = src[e];
    }
}

// ---------------- fused dual-GEMM: V = X @ [gcW | resW], gc half scaled by norm_s[row] ----
// X: [M, 128] row-major. gcW/resW: [128, SPLIT] row-major. V: [M, NOUT], NOUT = 2*SPLIT.
// Tile: BM=64, BN=64, BK=128 (full K). Block = 256 threads, 4x4 micro-tile.
// LDS: As 64x128 f32 (32KB) + Bs 128x64 f32 (32KB) = 64KB static.

template <int NOUT, int SPLIT>
__global__ __launch_bounds__(256) void gemm_kernel(
    const float* __restrict__ X, int M,
    const float* __restrict__ gcW, const float* __restrict__ resW,
    const float* __restrict__ norm_s, float* __restrict__ V) {
    __shared__ float As[64 * 128];
    __shared__ float Bs[128 * 64];

    const int bm0 = blockIdx.x * 64;
    const int by = blockIdx.y;
    const bool isGc = (by * 64) < SPLIT;
    const float* Bsrc = isGc ? gcW : resW;
    const int coloff = by * 64 - (isGc ? 0 : SPLIT);
    const int t = threadIdx.x;

    // Stage A: 64 rows x 128 cols = 2048 float4, 8 per thread, coalesced.
    #pragma unroll
    for (int i = 0; i < 8; i++) {
        int f = t + i * 256;
        int r = f >> 5;           // 0..63
        int c = (f & 31) * 4;     // 0..124
        int gm = bm0 + r;
        float4 val = make_float4(0.f, 0.f, 0.f, 0.f);
        if (gm < M) val = *(const float4*)(X + (size_t)gm * NFEAT + c);
        *(float4*)(As + r * 128 + c) = val;
    }
    // Stage B: 128 rows x 64 cols = 2048 float4, 8 per thread, coalesced.
    #pragma unroll
    for (int i = 0; i < 8; i++) {
        int f = t + i * 256;
        int r = f >> 4;           // 0..127
        int c = (f & 15) * 4;     // 0..60
        *(float4*)(Bs + r * 64 + c) = *(const float4*)(Bsrc + (size_t)r * SPLIT + coloff + c);
    }
    __syncthreads();

    const int tx = t & 15, ty = t >> 4;
    const int m0 = ty * 4, n0 = tx * 4;
    float acc[4][4] = {};

    #pragma unroll
    for (int k0 = 0; k0 < 128; k0 += 4) {
        float a[4][4], b[4][4];
        #pragma unroll
        for (int i = 0; i < 4; i++) {
            float4 a4 = *(const float4*)(As + (m0 + i) * 128 + k0);
            a[i][0] = a4.x; a[i][1] = a4.y; a[i][2] = a4.z; a[i][3] = a4.w;
        }
        #pragma unroll
        for (int j = 0; j < 4; j++) {
            float4 b4 = *(const float4*)(Bs + (k0 + j) * 64 + n0);
            b[j][0] = b4.x; b[j][1] = b4.y; b[j][2] = b4.z; b[j][3] = b4.w;
        }
        #pragma unroll
        for (int i = 0; i < 4; i++)
            #pragma unroll
            for (int kk = 0; kk < 4; kk++) {
                float av = a[i][kk];
                #pragma unroll
                for (int j = 0; j < 4; j++)
                    acc[i][j] = fmaf(av, b[kk][j], acc[i][j]);
            }
    }

    #pragma unroll
    for (int i = 0; i < 4; i++) {
        int gm = bm0 + m0 + i;
        if (gm >= M) continue;
        float s = isGc ? norm_s[gm] : 1.0f;
        float4 o;
        o.x = acc[i][0] * s; o.y = acc[i][1] * s;
        o.z = acc[i][2] * s; o.w = acc[i][3] * s;
        *(float4*)(V + (size_t)gm * NOUT + by * 64 + n0) = o;
    }
}

// ---------------- pull-mode SpMM + epilogue ----------------
// One wave per node. V row width = 64*VEC. Lanes 0..31 hold gc half, 32..63 residual half.
// out[node] = relu? ( norm_d[node]*Agg_gc + Agg_res + bias ), out width = 32*VEC.

template <int VEC, bool RELU>
__global__ __launch_bounds__(256) void spmm_kernel(
    const float* __restrict__ V, const int* __restrict__ row_ptr,
    const int* __restrict__ csr_src, const float* __restrict__ norm_d,
    const float* __restrict__ bias, float* __restrict__ out, int n) {
    int wid = (blockIdx.x * 256 + threadIdx.x) >> 6;
    int lane = threadIdx.x & 63;
    if (wid >= n) return;

    constexpr int W = 64 * VEC;
    float acc[VEC];
    #pragma unroll
    for (int c = 0; c < VEC; c++) acc[c] = 0.f;

    int e0 = row_ptr[wid];
    int e1 = row_ptr[wid + 1];
    for (int e = e0; e < e1; e++) {
        int s = csr_src[e];
        const float* p = V + (size_t)s * W + lane * VEC;
        if constexpr (VEC == 4) {
            float4 xv = *(const float4*)p;
            acc[0] += xv.x; acc[1] += xv.y; acc[2] += xv.z; acc[3] += xv.w;
        } else {
            float2 xv = *(const float2*)p;
            acc[0] += xv.x; acc[1] += xv.y;
        }
    }

    float part[VEC];
    #pragma unroll
    for (int c = 0; c < VEC; c++) part[c] = __shfl(acc[c], (lane + 32) & 63, 64);

    if (lane < 32) {
        float nd = norm_d[wid];
        float res[VEC];
        #pragma unroll
        for (int c = 0; c < VEC; c++) {
            float r = nd * acc[c] + part[c] + bias[lane * VEC + c];
            if (RELU) r = fmaxf(r, 0.f);
            res[c] = r;
        }
        float* po = out + (size_t)wid * (32 * VEC) + lane * VEC;
        if constexpr (VEC == 4) {
            float4 o; o.x = res[0]; o.y = res[1]; o.z = res[2]; o.w = res[3];
            *(float4*)po = o;
        } else {
            float2 o; o.x = res[0]; o.y = res[1];
            *(float2*)po = o;
        }
    }
}

// ---------------- launch ----------------

extern "C" void kernel_launch(void* const* d_in, const int* in_sizes, int n_in,
                              void* d_out, int out_size, void* d_ws, size_t ws_size,
                              hipStream_t stream) {
    const float* raw_x  = (const float*)d_in[0];
    const int*   src    = (const int*)d_in[1];
    const int*   dst    = (const int*)d_in[2];
    const float* gc_w0  = (const float*)d_in[3];
    const float* gc_b0  = (const float*)d_in[4];
    const float* gc_w1  = (const float*)d_in[5];
    const float* gc_b1  = (const float*)d_in[6];
    const float* gc_w2  = (const float*)d_in[7];
    const float* gc_b2  = (const float*)d_in[8];
    const float* res_w0 = (const float*)d_in[9];
    const float* res_w1 = (const float*)d_in[10];
    const float* res_w2 = (const float*)d_in[11];

    const int n  = in_sizes[0] / NFEAT;   // 100000
    const int ne = in_sizes[1];           // 1600000
    float* out = (float*)d_out;

    // workspace layout
    char* w = (char*)d_ws;
    float* V = (float*)w;        w += (size_t)n * 256 * sizeof(float);   // 102.4 MB
    float* X1 = (float*)w;       w += (size_t)n * 128 * sizeof(float);   // 51.2 MB
    float* norm_s = (float*)w;   w += (size_t)n * sizeof(float);
    float* norm_d = (float*)w;   w += (size_t)n * sizeof(float);
    int* out_cnt = (int*)w;      w += (size_t)n * sizeof(int);
    int* in_cnt = (int*)w;       w += (size_t)n * sizeof(int);
    int* row_ptr = (int*)w;      w += (size_t)(n + 1) * sizeof(int);
    int* cursor = (int*)w;       w += (size_t)n * sizeof(int);
    int* bsums = (int*)w;        w += 4096;
    int* csr_src = (int*)w;      w += (size_t)ne * sizeof(int);

    const int nb = (n + 1023) / 1024;

    // --- preprocessing: degrees, norms, CSR-by-dst ---
    zero_ints<<<(2 * n + 255) / 256, 256, 0, stream>>>(out_cnt, 2 * n); // out_cnt & in_cnt contiguous
    degree_kernel<<<(ne + 255) / 256, 256, 0, stream>>>(src, dst, ne, out_cnt, in_cnt);
    norm_kernel<<<(n + 255) / 256, 256, 0, stream>>>(out_cnt, in_cnt, norm_s, norm_d, n);
    scan_phase1<<<nb, 1024, 0, stream>>>(in_cnt, row_ptr, bsums, n);
    scan_phase2<<<1, 1024, 0, stream>>>(bsums, nb);
    scan_phase3<<<nb, 1024, 0, stream>>>(row_ptr, bsums, cursor, n, ne);
    scatter_kernel<<<(ne + 255) / 256, 256, 0, stream>>>(src, dst, ne, cursor, csr_src);

    const dim3 gemm_grid_wide((n + 63) / 64, 4);
    const dim3 gemm_grid_narrow((n + 63) / 64, 2);
    const int spmm_blocks = (n + 3) / 4;

    // --- layer 0: x1 = relu(norm_d*spmm(norm_s*(x@W0)) + spmm(x@R0) + b0) ---
    gemm_kernel<256, 128><<<gemm_grid_wide, 256, 0, stream>>>(raw_x, n, gc_w0, res_w0, norm_s, V);
    spmm_kernel<4, true><<<spmm_blocks, 256, 0, stream>>>(V, row_ptr, csr_src, norm_d, gc_b0, X1, n);

    // --- layer 1 (writes back into X1 after GEMM consumed it) ---
    gemm_kernel<256, 128><<<gemm_grid_wide, 256, 0, stream>>>(X1, n, gc_w1, res_w1, norm_s, V);
    spmm_kernel<4, true><<<spmm_blocks, 256, 0, stream>>>(V, row_ptr, csr_src, norm_d, gc_b1, X1, n);

    // --- layer 2: output 64-wide, no relu ---
    gemm_kernel<128, 64><<<gemm_grid_narrow, 256, 0, stream>>>(X1, n, gc_w2, res_w2, norm_s, V);
    spmm_kernel<2, false><<<spmm_blocks, 256, 0, stream>>>(V, row_ptr, csr_src, norm_d, gc_b2, out, n);
}

// Round 3
// 1240.747 us; speedup vs baseline: 6.5524x; 6.5524x over previous
//
#include <hip/hip_runtime.h>
#include <cstdint>
#include <cstddef>

#define NFEAT 128

// ---------------- preprocessing kernels ----------------

__global__ void zero_ints(int* __restrict__ p, int n) {
    int i = blockIdx.x * blockDim.x + threadIdx.x;
    if (i < n) p[i] = 0;
}

__global__ void degree_kernel(const int* __restrict__ src, const int* __restrict__ dst,
                              int ne, int* __restrict__ out_cnt, int* __restrict__ in_cnt) {
    int e = blockIdx.x * blockDim.x + threadIdx.x;
    if (e < ne) {
        atomicAdd(&out_cnt[src[e]], 1);
        atomicAdd(&in_cnt[dst[e]], 1);
    }
}

__global__ void norm_kernel(const int* __restrict__ out_cnt, const int* __restrict__ in_cnt,
                            float* __restrict__ norm_s, float* __restrict__ norm_d, int n) {
    int i = blockIdx.x * blockDim.x + threadIdx.x;
    if (i < n) {
        norm_s[i] = rsqrtf(fmaxf((float)out_cnt[i], 1.0f));
        norm_d[i] = rsqrtf(fmaxf((float)in_cnt[i], 1.0f));
    }
}

// Block-wise exclusive scan (Hillis-Steele), 1024 threads/block.
__global__ void scan_phase1(const int* __restrict__ cnt, int* __restrict__ excl,
                            int* __restrict__ bsums, int n) {
    __shared__ int tmp[1024];
    int tid = threadIdx.x;
    int gid = blockIdx.x * 1024 + tid;
    int v = (gid < n) ? cnt[gid] : 0;
    tmp[tid] = v;
    for (int off = 1; off < 1024; off <<= 1) {
        __syncthreads();
        int t = (tid >= off) ? tmp[tid - off] : 0;
        __syncthreads();
        tmp[tid] += t;
    }
    __syncthreads();
    if (gid < n) excl[gid] = tmp[tid] - v;
    if (tid == 0) bsums[blockIdx.x] = tmp[1023];
}

__global__ void scan_phase2(int* __restrict__ bsums, int nb) {
    __shared__ int tmp[1024];
    int tid = threadIdx.x;
    int v = (tid < nb) ? bsums[tid] : 0;
    tmp[tid] = v;
    for (int off = 1; off < 1024; off <<= 1) {
        __syncthreads();
        int t = (tid >= off) ? tmp[tid - off] : 0;
        __syncthreads();
        tmp[tid] += t;
    }
    __syncthreads();
    if (tid < nb) bsums[tid] = tmp[tid] - v;
}

__global__ void scan_phase3(int* __restrict__ row_ptr, const int* __restrict__ bsums,
                            int* __restrict__ cursor, int n, int ne) {
    int gid = blockIdx.x * 1024 + threadIdx.x;
    if (gid < n) {
        int r = row_ptr[gid] + bsums[blockIdx.x];
        row_ptr[gid] = r;
        cursor[gid] = r;
    }
    if (gid == 0) row_ptr[n] = ne;
}

__global__ void scatter_kernel(const int* __restrict__ src, const int* __restrict__ dst,
                               int ne, int* __restrict__ cursor, int* __restrict__ csr_src) {
    int e = blockIdx.x * blockDim.x + threadIdx.x;
    if (e < ne) {
        int d = dst[e];
        int p = atomicAdd(&cursor[d], 1);
        csr_src[p] = src[e];
    }
}

// ---------------- fused dual-GEMM: V = X @ [gcW | resW], gc half scaled by norm_s[row] ----
// X: [M, 128] row-major. gcW/resW: [128, SPLIT] row-major. V: [M, NOUT], NOUT = 2*SPLIT.
// Tile: BM=64, BN=64, BK=128 (full K). Block = 256 threads, 4x4 micro-tile.
// LDS: As 64x128 f32 (32KB) + Bs 128x64 f32 (32KB) = 64KB static.
// __launch_bounds__(256,4): cap VGPRs at ~128 — round-1 build used 256 VGPRs and
// spilled ~8 GB/dispatch to scratch (WRITE_SIZE 3.4e6 KB). Bounded unroll (2) keeps
// the hoisted live set ~80 regs.

template <int NOUT, int SPLIT>
__global__ __launch_bounds__(256, 4) void gemm_kernel(
    const float* __restrict__ X, int M,
    const float* __restrict__ gcW, const float* __restrict__ resW,
    const float* __restrict__ norm_s, float* __restrict__ V) {
    __shared__ float As[64 * 128];
    __shared__ float Bs[128 * 64];

    const int bm0 = blockIdx.x * 64;
    const int by = blockIdx.y;
    const bool isGc = (by * 64) < SPLIT;
    const float* Bsrc = isGc ? gcW : resW;
    const int coloff = by * 64 - (isGc ? 0 : SPLIT);
    const int t = threadIdx.x;

    // Stage A: 64 rows x 128 cols = 2048 float4, 8 per thread, coalesced.
    #pragma unroll
    for (int i = 0; i < 8; i++) {
        int f = t + i * 256;
        int r = f >> 5;           // 0..63
        int c = (f & 31) * 4;     // 0..124
        int gm = bm0 + r;
        float4 val = make_float4(0.f, 0.f, 0.f, 0.f);
        if (gm < M) val = *(const float4*)(X + (size_t)gm * NFEAT + c);
        *(float4*)(As + r * 128 + c) = val;
    }
    // Stage B: 128 rows x 64 cols = 2048 float4, 8 per thread, coalesced.
    #pragma unroll
    for (int i = 0; i < 8; i++) {
        int f = t + i * 256;
        int r = f >> 4;           // 0..127
        int c = (f & 15) * 4;     // 0..60
        *(float4*)(Bs + r * 64 + c) = *(const float4*)(Bsrc + (size_t)r * SPLIT + coloff + c);
    }
    __syncthreads();

    const int tx = t & 15, ty = t >> 4;
    const int m0 = ty * 4, n0 = tx * 4;
    float acc[4][4] = {};

    #pragma unroll 2
    for (int k0 = 0; k0 < 128; k0 += 4) {
        float4 a4[4], b4[4];
        #pragma unroll
        for (int i = 0; i < 4; i++)
            a4[i] = *(const float4*)(As + (m0 + i) * 128 + k0);
        #pragma unroll
        for (int j = 0; j < 4; j++)
            b4[j] = *(const float4*)(Bs + (k0 + j) * 64 + n0);
        #pragma unroll
        for (int i = 0; i < 4; i++) {
            const float a0 = a4[i].x, a1 = a4[i].y, a2 = a4[i].z, a3 = a4[i].w;
            acc[i][0] = fmaf(a0, b4[0].x, acc[i][0]);
            acc[i][1] = fmaf(a0, b4[0].y, acc[i][1]);
            acc[i][2] = fmaf(a0, b4[0].z, acc[i][2]);
            acc[i][3] = fmaf(a0, b4[0].w, acc[i][3]);
            acc[i][0] = fmaf(a1, b4[1].x, acc[i][0]);
            acc[i][1] = fmaf(a1, b4[1].y, acc[i][1]);
            acc[i][2] = fmaf(a1, b4[1].z, acc[i][2]);
            acc[i][3] = fmaf(a1, b4[1].w, acc[i][3]);
            acc[i][0] = fmaf(a2, b4[2].x, acc[i][0]);
            acc[i][1] = fmaf(a2, b4[2].y, acc[i][1]);
            acc[i][2] = fmaf(a2, b4[2].z, acc[i][2]);
            acc[i][3] = fmaf(a2, b4[2].w, acc[i][3]);
            acc[i][0] = fmaf(a3, b4[3].x, acc[i][0]);
            acc[i][1] = fmaf(a3, b4[3].y, acc[i][1]);
            acc[i][2] = fmaf(a3, b4[3].z, acc[i][2]);
            acc[i][3] = fmaf(a3, b4[3].w, acc[i][3]);
        }
    }

    #pragma unroll
    for (int i = 0; i < 4; i++) {
        int gm = bm0 + m0 + i;
        if (gm >= M) continue;
        float s = isGc ? norm_s[gm] : 1.0f;
        float4 o;
        o.x = acc[i][0] * s; o.y = acc[i][1] * s;
        o.z = acc[i][2] * s; o.w = acc[i][3] * s;
        *(float4*)(V + (size_t)gm * NOUT + by * 64 + n0) = o;
    }
}

// ---------------- pull-mode SpMM + epilogue ----------------
// One wave per node. V row width = 64*VEC. Lanes 0..31 hold gc half, 32..63 residual half.
// out[node] = relu? ( norm_d[node]*Agg_gc + Agg_res + bias ), out width = 32*VEC.

template <int VEC, bool RELU>
__global__ __launch_bounds__(256) void spmm_kernel(
    const float* __restrict__ V, const int* __restrict__ row_ptr,
    const int* __restrict__ csr_src, const float* __restrict__ norm_d,
    const float* __restrict__ bias, float* __restrict__ out, int n) {
    int wid = (blockIdx.x * 256 + threadIdx.x) >> 6;
    int lane = threadIdx.x & 63;
    if (wid >= n) return;

    constexpr int W = 64 * VEC;
    float acc[VEC];
    #pragma unroll
    for (int c = 0; c < VEC; c++) acc[c] = 0.f;

    int e0 = row_ptr[wid];
    int e1 = row_ptr[wid + 1];
    for (int e = e0; e < e1; e++) {
        int s = csr_src[e];
        const float* p = V + (size_t)s * W + lane * VEC;
        if constexpr (VEC == 4) {
            float4 xv = *(const float4*)p;
            acc[0] += xv.x; acc[1] += xv.y; acc[2] += xv.z; acc[3] += xv.w;
        } else {
            float2 xv = *(const float2*)p;
            acc[0] += xv.x; acc[1] += xv.y;
        }
    }

    float part[VEC];
    #pragma unroll
    for (int c = 0; c < VEC; c++) part[c] = __shfl(acc[c], (lane + 32) & 63, 64);

    if (lane < 32) {
        float nd = norm_d[wid];
        float res[VEC];
        #pragma unroll
        for (int c = 0; c < VEC; c++) {
            float r = nd * acc[c] + part[c] + bias[lane * VEC + c];
            if (RELU) r = fmaxf(r, 0.f);
            res[c] = r;
        }
        float* po = out + (size_t)wid * (32 * VEC) + lane * VEC;
        if constexpr (VEC == 4) {
            float4 o; o.x = res[0]; o.y = res[1]; o.z = res[2]; o.w = res[3];
            *(float4*)po = o;
        } else {
            float2 o; o.x = res[0]; o.y = res[1];
            *(float2*)po = o;
        }
    }
}

// ---------------- launch ----------------

extern "C" void kernel_launch(void* const* d_in, const int* in_sizes, int n_in,
                              void* d_out, int out_size, void* d_ws, size_t ws_size,
                              hipStream_t stream) {
    const float* raw_x  = (const float*)d_in[0];
    const int*   src    = (const int*)d_in[1];
    const int*   dst    = (const int*)d_in[2];
    const float* gc_w0  = (const float*)d_in[3];
    const float* gc_b0  = (const float*)d_in[4];
    const float* gc_w1  = (const float*)d_in[5];
    const float* gc_b1  = (const float*)d_in[6];
    const float* gc_w2  = (const float*)d_in[7];
    const float* gc_b2  = (const float*)d_in[8];
    const float* res_w0 = (const float*)d_in[9];
    const float* res_w1 = (const float*)d_in[10];
    const float* res_w2 = (const float*)d_in[11];

    const int n  = in_sizes[0] / NFEAT;   // 100000
    const int ne = in_sizes[1];           // 1600000
    float* out = (float*)d_out;

    // workspace layout
    char* w = (char*)d_ws;
    float* V = (float*)w;        w += (size_t)n * 256 * sizeof(float);   // 102.4 MB
    float* X1 = (float*)w;       w += (size_t)n * 128 * sizeof(float);   // 51.2 MB
    float* norm_s = (float*)w;   w += (size_t)n * sizeof(float);
    float* norm_d = (float*)w;   w += (size_t)n * sizeof(float);
    int* out_cnt = (int*)w;      w += (size_t)n * sizeof(int);
    int* in_cnt = (int*)w;       w += (size_t)n * sizeof(int);
    int* row_ptr = (int*)w;      w += (size_t)(n + 1) * sizeof(int);
    int* cursor = (int*)w;       w += (size_t)n * sizeof(int);
    int* bsums = (int*)w;        w += 4096;
    int* csr_src = (int*)w;      w += (size_t)ne * sizeof(int);

    const int nb = (n + 1023) / 1024;

    // --- preprocessing: degrees, norms, CSR-by-dst ---
    zero_ints<<<(2 * n + 255) / 256, 256, 0, stream>>>(out_cnt, 2 * n); // out_cnt & in_cnt contiguous
    degree_kernel<<<(ne + 255) / 256, 256, 0, stream>>>(src, dst, ne, out_cnt, in_cnt);
    norm_kernel<<<(n + 255) / 256, 256, 0, stream>>>(out_cnt, in_cnt, norm_s, norm_d, n);
    scan_phase1<<<nb, 1024, 0, stream>>>(in_cnt, row_ptr, bsums, n);
    scan_phase2<<<1, 1024, 0, stream>>>(bsums, nb);
    scan_phase3<<<nb, 1024, 0, stream>>>(row_ptr, bsums, cursor, n, ne);
    scatter_kernel<<<(ne + 255) / 256, 256, 0, stream>>>(src, dst, ne, cursor, csr_src);

    const dim3 gemm_grid_wide((n + 63) / 64, 4);
    const dim3 gemm_grid_narrow((n + 63) / 64, 2);
    const int spmm_blocks = (n + 3) / 4;

    // --- layer 0: x1 = relu(norm_d*spmm(norm_s*(x@W0)) + spmm(x@R0) + b0) ---
    gemm_kernel<256, 128><<<gemm_grid_wide, 256, 0, stream>>>(raw_x, n, gc_w0, res_w0, norm_s, V);
    spmm_kernel<4, true><<<spmm_blocks, 256, 0, stream>>>(V, row_ptr, csr_src, norm_d, gc_b0, X1, n);

    // --- layer 1 (writes back into X1 after GEMM consumed it) ---
    gemm_kernel<256, 128><<<gemm_grid_wide, 256, 0, stream>>>(X1, n, gc_w1, res_w1, norm_s, V);
    spmm_kernel<4, true><<<spmm_blocks, 256, 0, stream>>>(V, row_ptr, csr_src, norm_d, gc_b1, X1, n);

    // --- layer 2: output 64-wide, no relu ---
    gemm_kernel<128, 64><<<gemm_grid_narrow, 256, 0, stream>>>(X1, n, gc_w2, res_w2, norm_s, V);
    spmm_kernel<2, false><<<spmm_blocks, 256, 0, stream>>>(V, row_ptr, csr_src, norm_d, gc_b2, out, n);
}

// Round 4
// 1109.523 us; speedup vs baseline: 7.3273x; 1.1183x over previous
//
#include <hip/hip_runtime.h>
#include <cstdint>
#include <cstddef>

#define NFEAT 128

// bf16 <-> f32 helpers (RNE, no NaN handling needed — activations are finite)
__device__ __forceinline__ unsigned short f2bf(float x) {
    union { float f; unsigned u; } v; v.f = x;
    unsigned r = v.u + 0x7fffu + ((v.u >> 16) & 1u);
    return (unsigned short)(r >> 16);
}
__device__ __forceinline__ float bf2f(unsigned short b) {
    union { unsigned u; float f; } v; v.u = ((unsigned)b) << 16;
    return v.f;
}

// ---------------- preprocessing kernels ----------------

__global__ void zero_ints(int* __restrict__ p, int n) {
    int i = blockIdx.x * blockDim.x + threadIdx.x;
    if (i < n) p[i] = 0;
}

__global__ void cast_bf16_kernel(const float* __restrict__ x, unsigned short* __restrict__ y, int n4) {
    int i = blockIdx.x * blockDim.x + threadIdx.x;
    if (i < n4) {
        float4 v = ((const float4*)x)[i];
        ushort4 o;
        o.x = f2bf(v.x); o.y = f2bf(v.y); o.z = f2bf(v.z); o.w = f2bf(v.w);
        ((ushort4*)y)[i] = o;
    }
}

__global__ void degree_kernel(const int* __restrict__ src, const int* __restrict__ dst,
                              int ne, int* __restrict__ out_cnt, int* __restrict__ in_cnt) {
    int e = blockIdx.x * blockDim.x + threadIdx.x;
    if (e < ne) {
        atomicAdd(&out_cnt[src[e]], 1);
        atomicAdd(&in_cnt[dst[e]], 1);
    }
}

__global__ void norm_kernel(const int* __restrict__ out_cnt, const int* __restrict__ in_cnt,
                            float* __restrict__ norm_s, float* __restrict__ norm_d, int n) {
    int i = blockIdx.x * blockDim.x + threadIdx.x;
    if (i < n) {
        norm_s[i] = rsqrtf(fmaxf((float)out_cnt[i], 1.0f));
        norm_d[i] = rsqrtf(fmaxf((float)in_cnt[i], 1.0f));
    }
}

// Block-wise exclusive scan (Hillis-Steele), 1024 threads/block.
__global__ void scan_phase1(const int* __restrict__ cnt, int* __restrict__ excl,
                            int* __restrict__ bsums, int n) {
    __shared__ int tmp[1024];
    int tid = threadIdx.x;
    int gid = blockIdx.x * 1024 + tid;
    int v = (gid < n) ? cnt[gid] : 0;
    tmp[tid] = v;
    for (int off = 1; off < 1024; off <<= 1) {
        __syncthreads();
        int t = (tid >= off) ? tmp[tid - off] : 0;
        __syncthreads();
        tmp[tid] += t;
    }
    __syncthreads();
    if (gid < n) excl[gid] = tmp[tid] - v;
    if (tid == 0) bsums[blockIdx.x] = tmp[1023];
}

__global__ void scan_phase2(int* __restrict__ bsums, int nb) {
    __shared__ int tmp[1024];
    int tid = threadIdx.x;
    int v = (tid < nb) ? bsums[tid] : 0;
    tmp[tid] = v;
    for (int off = 1; off < 1024; off <<= 1) {
        __syncthreads();
        int t = (tid >= off) ? tmp[tid - off] : 0;
        __syncthreads();
        tmp[tid] += t;
    }
    __syncthreads();
    if (tid < nb) bsums[tid] = tmp[tid] - v;
}

__global__ void scan_phase3(int* __restrict__ row_ptr, const int* __restrict__ bsums,
                            int* __restrict__ cursor, int n, int ne) {
    int gid = blockIdx.x * 1024 + threadIdx.x;
    if (gid < n) {
        int r = row_ptr[gid] + bsums[blockIdx.x];
        row_ptr[gid] = r;
        cursor[gid] = r;
    }
    if (gid == 0) row_ptr[n] = ne;
}

__global__ void scatter_kernel(const int* __restrict__ src, const int* __restrict__ dst,
                               int ne, int* __restrict__ cursor, int* __restrict__ csr_src) {
    int e = blockIdx.x * blockDim.x + threadIdx.x;
    if (e < ne) {
        int d = dst[e];
        int p = atomicAdd(&cursor[d], 1);
        csr_src[p] = src[e];
    }
}

// ---------------- fused dual-GEMM: V = X @ [gcW | resW], gc half scaled by norm_s[row] ----
// X: [M, 128] bf16 row-major. gcW/resW: [128, SPLIT] fp32 row-major.
// V: [M, NOUT] bf16, NOUT = 2*SPLIT. Math is fp32 FMA (LDS tiles converted to f32).
// Tile: BM=64, BN=64, BK=128 (full K). Block = 256 threads, 4x4 micro-tile.
// __launch_bounds__(256,4) + unroll 2: keeps VGPR <=128 (round-1 build at 256 VGPR
// spilled ~8 GB/dispatch to scratch).

template <int NOUT, int SPLIT>
__global__ __launch_bounds__(256, 4) void gemm_kernel(
    const unsigned short* __restrict__ X, int M,
    const float* __restrict__ gcW, const float* __restrict__ resW,
    const float* __restrict__ norm_s, unsigned short* __restrict__ V) {
    __shared__ float As[64 * 128];
    __shared__ float Bs[128 * 64];

    const int bm0 = blockIdx.x * 64;
    const int by = blockIdx.y;
    const bool isGc = (by * 64) < SPLIT;
    const float* Bsrc = isGc ? gcW : resW;
    const int coloff = by * 64 - (isGc ? 0 : SPLIT);
    const int t = threadIdx.x;

    // Stage A: 64 rows x 128 bf16 = 1024 x ushort8(16B), 4 per thread, coalesced.
    #pragma unroll
    for (int i = 0; i < 4; i++) {
        int f = t + i * 256;      // 0..1023
        int r = f >> 4;           // 0..63
        int c = (f & 15) * 8;     // 0..120
        int gm = bm0 + r;
        ushort4 lo = make_ushort4(0, 0, 0, 0), hi = make_ushort4(0, 0, 0, 0);
        if (gm < M) {
            const ushort4* p = (const ushort4*)(X + (size_t)gm * NFEAT + c);
            lo = p[0]; hi = p[1];
        }
        float* d = As + r * 128 + c;
        d[0] = bf2f(lo.x); d[1] = bf2f(lo.y); d[2] = bf2f(lo.z); d[3] = bf2f(lo.w);
        d[4] = bf2f(hi.x); d[5] = bf2f(hi.y); d[6] = bf2f(hi.z); d[7] = bf2f(hi.w);
    }
    // Stage B: 128 rows x 64 f32 = 2048 float4, 8 per thread, coalesced.
    #pragma unroll
    for (int i = 0; i < 8; i++) {
        int f = t + i * 256;
        int r = f >> 4;           // 0..127
        int c = (f & 15) * 4;     // 0..60
        *(float4*)(Bs + r * 64 + c) = *(const float4*)(Bsrc + (size_t)r * SPLIT + coloff + c);
    }
    __syncthreads();

    const int tx = t & 15, ty = t >> 4;
    const int m0 = ty * 4, n0 = tx * 4;
    float acc[4][4] = {};

    #pragma unroll 2
    for (int k0 = 0; k0 < 128; k0 += 4) {
        float4 a4[4], b4[4];
        #pragma unroll
        for (int i = 0; i < 4; i++)
            a4[i] = *(const float4*)(As + (m0 + i) * 128 + k0);
        #pragma unroll
        for (int j = 0; j < 4; j++)
            b4[j] = *(const float4*)(Bs + (k0 + j) * 64 + n0);
        #pragma unroll
        for (int i = 0; i < 4; i++) {
            const float a0 = a4[i].x, a1 = a4[i].y, a2 = a4[i].z, a3 = a4[i].w;
            acc[i][0] = fmaf(a0, b4[0].x, acc[i][0]);
            acc[i][1] = fmaf(a0, b4[0].y, acc[i][1]);
            acc[i][2] = fmaf(a0, b4[0].z, acc[i][2]);
            acc[i][3] = fmaf(a0, b4[0].w, acc[i][3]);
            acc[i][0] = fmaf(a1, b4[1].x, acc[i][0]);
            acc[i][1] = fmaf(a1, b4[1].y, acc[i][1]);
            acc[i][2] = fmaf(a1, b4[1].z, acc[i][2]);
            acc[i][3] = fmaf(a1, b4[1].w, acc[i][3]);
            acc[i][0] = fmaf(a2, b4[2].x, acc[i][0]);
            acc[i][1] = fmaf(a2, b4[2].y, acc[i][1]);
            acc[i][2] = fmaf(a2, b4[2].z, acc[i][2]);
            acc[i][3] = fmaf(a2, b4[2].w, acc[i][3]);
            acc[i][0] = fmaf(a3, b4[3].x, acc[i][0]);
            acc[i][1] = fmaf(a3, b4[3].y, acc[i][1]);
            acc[i][2] = fmaf(a3, b4[3].z, acc[i][2]);
            acc[i][3] = fmaf(a3, b4[3].w, acc[i][3]);
        }
    }

    #pragma unroll
    for (int i = 0; i < 4; i++) {
        int gm = bm0 + m0 + i;
        if (gm >= M) continue;
        float s = isGc ? norm_s[gm] : 1.0f;
        ushort4 o;
        o.x = f2bf(acc[i][0] * s); o.y = f2bf(acc[i][1] * s);
        o.z = f2bf(acc[i][2] * s); o.w = f2bf(acc[i][3] * s);
        *(ushort4*)(V + (size_t)gm * NOUT + by * 64 + n0) = o;
    }
}

// ---------------- pull-mode SpMM + epilogue ----------------
// One wave per node. V row = 64*VEC bf16. Lanes 0..31 gc half, 32..63 residual half.
// out[node] = relu? ( norm_d[node]*Agg_gc + Agg_res + bias ); fp32 accumulation.
// OUT_BF16: write bf16 activations (layers 0/1); else fp32 (final layer).

template <int VEC, bool RELU, bool OUT_BF16>
__global__ __launch_bounds__(256) void spmm_kernel(
    const unsigned short* __restrict__ V, const int* __restrict__ row_ptr,
    const int* __restrict__ csr_src, const float* __restrict__ norm_d,
    const float* __restrict__ bias, void* __restrict__ outv, int n) {
    int wid = (blockIdx.x * 256 + threadIdx.x) >> 6;
    int lane = threadIdx.x & 63;
    if (wid >= n) return;

    constexpr int W = 64 * VEC;
    float acc[VEC];
    #pragma unroll
    for (int c = 0; c < VEC; c++) acc[c] = 0.f;

    int e0 = row_ptr[wid];
    int e1 = row_ptr[wid + 1];
    for (int e = e0; e < e1; e++) {
        int s = csr_src[e];
        const unsigned short* p = V + (size_t)s * W + lane * VEC;
        if constexpr (VEC == 4) {
            ushort4 q = *(const ushort4*)p;
            acc[0] += bf2f(q.x); acc[1] += bf2f(q.y);
            acc[2] += bf2f(q.z); acc[3] += bf2f(q.w);
        } else {
            ushort2 q = *(const ushort2*)p;
            acc[0] += bf2f(q.x); acc[1] += bf2f(q.y);
        }
    }

    float part[VEC];
    #pragma unroll
    for (int c = 0; c < VEC; c++) part[c] = __shfl(acc[c], (lane + 32) & 63, 64);

    if (lane < 32) {
        float nd = norm_d[wid];
        float res[VEC];
        #pragma unroll
        for (int c = 0; c < VEC; c++) {
            float r = nd * acc[c] + part[c] + bias[lane * VEC + c];
            if (RELU) r = fmaxf(r, 0.f);
            res[c] = r;
        }
        if constexpr (OUT_BF16) {
            unsigned short* po = (unsigned short*)outv + (size_t)wid * (32 * VEC) + lane * VEC;
            if constexpr (VEC == 4) {
                ushort4 o;
                o.x = f2bf(res[0]); o.y = f2bf(res[1]);
                o.z = f2bf(res[2]); o.w = f2bf(res[3]);
                *(ushort4*)po = o;
            } else {
                ushort2 o; o.x = f2bf(res[0]); o.y = f2bf(res[1]);
                *(ushort2*)po = o;
            }
        } else {
            float* po = (float*)outv + (size_t)wid * (32 * VEC) + lane * VEC;
            if constexpr (VEC == 4) {
                float4 o; o.x = res[0]; o.y = res[1]; o.z = res[2]; o.w = res[3];
                *(float4*)po = o;
            } else {
                float2 o; o.x = res[0]; o.y = res[1];
                *(float2*)po = o;
            }
        }
    }
}

// ---------------- launch ----------------

extern "C" void kernel_launch(void* const* d_in, const int* in_sizes, int n_in,
                              void* d_out, int out_size, void* d_ws, size_t ws_size,
                              hipStream_t stream) {
    const float* raw_x  = (const float*)d_in[0];
    const int*   src    = (const int*)d_in[1];
    const int*   dst    = (const int*)d_in[2];
    const float* gc_w0  = (const float*)d_in[3];
    const float* gc_b0  = (const float*)d_in[4];
    const float* gc_w1  = (const float*)d_in[5];
    const float* gc_b1  = (const float*)d_in[6];
    const float* gc_w2  = (const float*)d_in[7];
    const float* gc_b2  = (const float*)d_in[8];
    const float* res_w0 = (const float*)d_in[9];
    const float* res_w1 = (const float*)d_in[10];
    const float* res_w2 = (const float*)d_in[11];

    const int n  = in_sizes[0] / NFEAT;   // 100000
    const int ne = in_sizes[1];           // 1600000
    float* out = (float*)d_out;

    // workspace layout (all bf16 activations)
    char* w = (char*)d_ws;
    unsigned short* V   = (unsigned short*)w; w += (size_t)n * 256 * sizeof(unsigned short); // 51.2 MB
    unsigned short* Xb  = (unsigned short*)w; w += (size_t)n * 128 * sizeof(unsigned short); // 25.6 MB
    unsigned short* X1b = (unsigned short*)w; w += (size_t)n * 128 * sizeof(unsigned short); // 25.6 MB
    float* norm_s = (float*)w;   w += (size_t)n * sizeof(float);
    float* norm_d = (float*)w;   w += (size_t)n * sizeof(float);
    int* out_cnt = (int*)w;      w += (size_t)n * sizeof(int);
    int* in_cnt = (int*)w;       w += (size_t)n * sizeof(int);
    int* row_ptr = (int*)w;      w += (size_t)(n + 1) * sizeof(int);
    int* cursor = (int*)w;       w += (size_t)n * sizeof(int);
    int* bsums = (int*)w;        w += 4096;
    int* csr_src = (int*)w;      w += (size_t)ne * sizeof(int);

    const int nb = (n + 1023) / 1024;

    // --- preprocessing: bf16 cast, degrees, norms, CSR-by-dst ---
    cast_bf16_kernel<<<(n * (NFEAT / 4) + 255) / 256, 256, 0, stream>>>(raw_x, Xb, n * (NFEAT / 4));
    zero_ints<<<(2 * n + 255) / 256, 256, 0, stream>>>(out_cnt, 2 * n); // out_cnt & in_cnt contiguous
    degree_kernel<<<(ne + 255) / 256, 256, 0, stream>>>(src, dst, ne, out_cnt, in_cnt);
    norm_kernel<<<(n + 255) / 256, 256, 0, stream>>>(out_cnt, in_cnt, norm_s, norm_d, n);
    scan_phase1<<<nb, 1024, 0, stream>>>(in_cnt, row_ptr, bsums, n);
    scan_phase2<<<1, 1024, 0, stream>>>(bsums, nb);
    scan_phase3<<<nb, 1024, 0, stream>>>(row_ptr, bsums, cursor, n, ne);
    scatter_kernel<<<(ne + 255) / 256, 256, 0, stream>>>(src, dst, ne, cursor, csr_src);

    const dim3 gemm_grid_wide((n + 63) / 64, 4);
    const dim3 gemm_grid_narrow((n + 63) / 64, 2);
    const int spmm_blocks = (n + 3) / 4;

    // --- layer 0: x1 = relu(norm_d*spmm(norm_s*(x@W0)) + spmm(x@R0) + b0) ---
    gemm_kernel<256, 128><<<gemm_grid_wide, 256, 0, stream>>>(Xb, n, gc_w0, res_w0, norm_s, V);
    spmm_kernel<4, true, true><<<spmm_blocks, 256, 0, stream>>>(V, row_ptr, csr_src, norm_d, gc_b0, X1b, n);

    // --- layer 1 ---
    gemm_kernel<256, 128><<<gemm_grid_wide, 256, 0, stream>>>(X1b, n, gc_w1, res_w1, norm_s, V);
    spmm_kernel<4, true, true><<<spmm_blocks, 256, 0, stream>>>(V, row_ptr, csr_src, norm_d, gc_b1, X1b, n);

    // --- layer 2: output 64-wide fp32, no relu ---
    gemm_kernel<128, 64><<<gemm_grid_narrow, 256, 0, stream>>>(X1b, n, gc_w2, res_w2, norm_s, V);
    spmm_kernel<2, false, false><<<spmm_blocks, 256, 0, stream>>>(V, row_ptr, csr_src, norm_d, gc_b2, out, n);
}

// Round 5
// 913.747 us; speedup vs baseline: 8.8973x; 1.2143x over previous
//
#include <hip/hip_runtime.h>
#include <cstdint>
#include <cstddef>

#define NFEAT 128

// bf16 <-> f32 helpers (RNE, no NaN handling needed — activations are finite)
__device__ __forceinline__ unsigned short f2bf(float x) {
    union { float f; unsigned u; } v; v.f = x;
    unsigned r = v.u + 0x7fffu + ((v.u >> 16) & 1u);
    return (unsigned short)(r >> 16);
}
__device__ __forceinline__ float bf2f(unsigned short b) {
    union { unsigned u; float f; } v; v.u = ((unsigned)b) << 16;
    return v.f;
}

// ---------------- preprocessing kernels ----------------

__global__ void zero_ints(int* __restrict__ p, int n) {
    int i = blockIdx.x * blockDim.x + threadIdx.x;
    if (i < n) p[i] = 0;
}

__global__ void cast_bf16_kernel(const float* __restrict__ x, unsigned short* __restrict__ y, int n4) {
    int i = blockIdx.x * blockDim.x + threadIdx.x;
    if (i < n4) {
        float4 v = ((const float4*)x)[i];
        ushort4 o;
        o.x = f2bf(v.x); o.y = f2bf(v.y); o.z = f2bf(v.z); o.w = f2bf(v.w);
        ((ushort4*)y)[i] = o;
    }
}

__global__ void degree_kernel(const int* __restrict__ src, const int* __restrict__ dst,
                              int ne, int* __restrict__ out_cnt, int* __restrict__ in_cnt) {
    int e = blockIdx.x * blockDim.x + threadIdx.x;
    if (e < ne) {
        atomicAdd(&out_cnt[src[e]], 1);
        atomicAdd(&in_cnt[dst[e]], 1);
    }
}

__global__ void norm_kernel(const int* __restrict__ out_cnt, const int* __restrict__ in_cnt,
                            float* __restrict__ norm_s, float* __restrict__ norm_d, int n) {
    int i = blockIdx.x * blockDim.x + threadIdx.x;
    if (i < n) {
        norm_s[i] = rsqrtf(fmaxf((float)out_cnt[i], 1.0f));
        norm_d[i] = rsqrtf(fmaxf((float)in_cnt[i], 1.0f));
    }
}

// Block-wise exclusive scan (Hillis-Steele), 1024 threads/block.
__global__ void scan_phase1(const int* __restrict__ cnt, int* __restrict__ excl,
                            int* __restrict__ bsums, int n) {
    __shared__ int tmp[1024];
    int tid = threadIdx.x;
    int gid = blockIdx.x * 1024 + tid;
    int v = (gid < n) ? cnt[gid] : 0;
    tmp[tid] = v;
    for (int off = 1; off < 1024; off <<= 1) {
        __syncthreads();
        int t = (tid >= off) ? tmp[tid - off] : 0;
        __syncthreads();
        tmp[tid] += t;
    }
    __syncthreads();
    if (gid < n) excl[gid] = tmp[tid] - v;
    if (tid == 0) bsums[blockIdx.x] = tmp[1023];
}

__global__ void scan_phase2(int* __restrict__ bsums, int nb) {
    __shared__ int tmp[1024];
    int tid = threadIdx.x;
    int v = (tid < nb) ? bsums[tid] : 0;
    tmp[tid] = v;
    for (int off = 1; off < 1024; off <<= 1) {
        __syncthreads();
        int t = (tid >= off) ? tmp[tid - off] : 0;
        __syncthreads();
        tmp[tid] += t;
    }
    __syncthreads();
    if (tid < nb) bsums[tid] = tmp[tid] - v;
}

__global__ void scan_phase3(int* __restrict__ row_ptr, const int* __restrict__ bsums,
                            int* __restrict__ cursor, int n, int ne) {
    int gid = blockIdx.x * 1024 + threadIdx.x;
    if (gid < n) {
        int r = row_ptr[gid] + bsums[blockIdx.x];
        row_ptr[gid] = r;
        cursor[gid] = r;
    }
    if (gid == 0) row_ptr[n] = ne;
}

__global__ void scatter_kernel(const int* __restrict__ src, const int* __restrict__ dst,
                               int ne, int* __restrict__ cursor, int* __restrict__ csr_src) {
    int e = blockIdx.x * blockDim.x + threadIdx.x;
    if (e < ne) {
        int d = dst[e];
        int p = atomicAdd(&cursor[d], 1);
        csr_src[p] = src[e];
    }
}

// ---------------- fused dual-GEMM: V = X @ [gcW | resW], gc half scaled by norm_s[row] ----
// X: [M, 128] bf16 row-major. gcW/resW: [128, SPLIT] fp32 row-major.
// V: [M, NOUT] bf16, NOUT = 2*SPLIT. Math is fp32 FMA (LDS tiles converted to f32).
// Tile: BM=64, BN=64, BK=128 (full K). Block = 256 threads, 4x4 micro-tile.
// __launch_bounds__(256,4) + unroll 2: keeps VGPR <=128 (round-1 build at 256 VGPR
// spilled ~8 GB/dispatch to scratch).

template <int NOUT, int SPLIT>
__global__ __launch_bounds__(256, 4) void gemm_kernel(
    const unsigned short* __restrict__ X, int M,
    const float* __restrict__ gcW, const float* __restrict__ resW,
    const float* __restrict__ norm_s, unsigned short* __restrict__ V) {
    __shared__ float As[64 * 128];
    __shared__ float Bs[128 * 64];

    const int bm0 = blockIdx.x * 64;
    const int by = blockIdx.y;
    const bool isGc = (by * 64) < SPLIT;
    const float* Bsrc = isGc ? gcW : resW;
    const int coloff = by * 64 - (isGc ? 0 : SPLIT);
    const int t = threadIdx.x;

    // Stage A: 64 rows x 128 bf16 = 1024 x ushort8(16B), 4 per thread, coalesced.
    #pragma unroll
    for (int i = 0; i < 4; i++) {
        int f = t + i * 256;      // 0..1023
        int r = f >> 4;           // 0..63
        int c = (f & 15) * 8;     // 0..120
        int gm = bm0 + r;
        ushort4 lo = make_ushort4(0, 0, 0, 0), hi = make_ushort4(0, 0, 0, 0);
        if (gm < M) {
            const ushort4* p = (const ushort4*)(X + (size_t)gm * NFEAT + c);
            lo = p[0]; hi = p[1];
        }
        float* d = As + r * 128 + c;
        d[0] = bf2f(lo.x); d[1] = bf2f(lo.y); d[2] = bf2f(lo.z); d[3] = bf2f(lo.w);
        d[4] = bf2f(hi.x); d[5] = bf2f(hi.y); d[6] = bf2f(hi.z); d[7] = bf2f(hi.w);
    }
    // Stage B: 128 rows x 64 f32 = 2048 float4, 8 per thread, coalesced.
    #pragma unroll
    for (int i = 0; i < 8; i++) {
        int f = t + i * 256;
        int r = f >> 4;           // 0..127
        int c = (f & 15) * 4;     // 0..60
        *(float4*)(Bs + r * 64 + c) = *(const float4*)(Bsrc + (size_t)r * SPLIT + coloff + c);
    }
    __syncthreads();

    const int tx = t & 15, ty = t >> 4;
    const int m0 = ty * 4, n0 = tx * 4;
    float acc[4][4] = {};

    #pragma unroll 2
    for (int k0 = 0; k0 < 128; k0 += 4) {
        float4 a4[4], b4[4];
        #pragma unroll
        for (int i = 0; i < 4; i++)
            a4[i] = *(const float4*)(As + (m0 + i) * 128 + k0);
        #pragma unroll
        for (int j = 0; j < 4; j++)
            b4[j] = *(const float4*)(Bs + (k0 + j) * 64 + n0);
        #pragma unroll
        for (int i = 0; i < 4; i++) {
            const float a0 = a4[i].x, a1 = a4[i].y, a2 = a4[i].z, a3 = a4[i].w;
            acc[i][0] = fmaf(a0, b4[0].x, acc[i][0]);
            acc[i][1] = fmaf(a0, b4[0].y, acc[i][1]);
            acc[i][2] = fmaf(a0, b4[0].z, acc[i][2]);
            acc[i][3] = fmaf(a0, b4[0].w, acc[i][3]);
            acc[i][0] = fmaf(a1, b4[1].x, acc[i][0]);
            acc[i][1] = fmaf(a1, b4[1].y, acc[i][1]);
            acc[i][2] = fmaf(a1, b4[1].z, acc[i][2]);
            acc[i][3] = fmaf(a1, b4[1].w, acc[i][3]);
            acc[i][0] = fmaf(a2, b4[2].x, acc[i][0]);
            acc[i][1] = fmaf(a2, b4[2].y, acc[i][1]);
            acc[i][2] = fmaf(a2, b4[2].z, acc[i][2]);
            acc[i][3] = fmaf(a2, b4[2].w, acc[i][3]);
            acc[i][0] = fmaf(a3, b4[3].x, acc[i][0]);
            acc[i][1] = fmaf(a3, b4[3].y, acc[i][1]);
            acc[i][2] = fmaf(a3, b4[3].z, acc[i][2]);
            acc[i][3] = fmaf(a3, b4[3].w, acc[i][3]);
        }
    }

    #pragma unroll
    for (int i = 0; i < 4; i++) {
        int gm = bm0 + m0 + i;
        if (gm >= M) continue;
        float s = isGc ? norm_s[gm] : 1.0f;
        ushort4 o;
        o.x = f2bf(acc[i][0] * s); o.y = f2bf(acc[i][1] * s);
        o.z = f2bf(acc[i][2] * s); o.w = f2bf(acc[i][3] * s);
        *(ushort4*)(V + (size_t)gm * NOUT + by * 64 + n0) = o;
    }
}

// ---------------- pull-mode SpMM + epilogue ----------------
// One wave per node. V row = 64*VEC bf16. Lanes 0..31 gc half, 32..63 residual half.
// Edge loop unrolled x4 with batched independent gathers: round-4 profile showed
// latency-bound gather (hbm 30%, VALU 23%, ~1 outstanding 512B load/wave).
// out[node] = relu? ( norm_d[node]*Agg_gc + Agg_res + bias ); fp32 accumulation.

template <int VEC, bool RELU, bool OUT_BF16>
__global__ __launch_bounds__(256) void spmm_kernel(
    const unsigned short* __restrict__ V, const int* __restrict__ row_ptr,
    const int* __restrict__ csr_src, const float* __restrict__ norm_d,
    const float* __restrict__ bias, void* __restrict__ outv, int n) {
    int wid = (blockIdx.x * 256 + threadIdx.x) >> 6;
    int lane = threadIdx.x & 63;
    if (wid >= n) return;

    constexpr int W = 64 * VEC;
    float acc[VEC];
    #pragma unroll
    for (int c = 0; c < VEC; c++) acc[c] = 0.f;

    const int e0 = row_ptr[wid];
    const int e1 = row_ptr[wid + 1];
    const unsigned short* Vl = V + (size_t)lane * VEC;

    int e = e0;
    if constexpr (VEC == 4) {
        for (; e + 4 <= e1; e += 4) {
            int s0 = csr_src[e];
            int s1 = csr_src[e + 1];
            int s2 = csr_src[e + 2];
            int s3 = csr_src[e + 3];
            ushort4 q0 = *(const ushort4*)(Vl + (size_t)s0 * W);
            ushort4 q1 = *(const ushort4*)(Vl + (size_t)s1 * W);
            ushort4 q2 = *(const ushort4*)(Vl + (size_t)s2 * W);
            ushort4 q3 = *(const ushort4*)(Vl + (size_t)s3 * W);
            acc[0] += (bf2f(q0.x) + bf2f(q1.x)) + (bf2f(q2.x) + bf2f(q3.x));
            acc[1] += (bf2f(q0.y) + bf2f(q1.y)) + (bf2f(q2.y) + bf2f(q3.y));
            acc[2] += (bf2f(q0.z) + bf2f(q1.z)) + (bf2f(q2.z) + bf2f(q3.z));
            acc[3] += (bf2f(q0.w) + bf2f(q1.w)) + (bf2f(q2.w) + bf2f(q3.w));
        }
        for (; e < e1; e++) {
            int s = csr_src[e];
            ushort4 q = *(const ushort4*)(Vl + (size_t)s * W);
            acc[0] += bf2f(q.x); acc[1] += bf2f(q.y);
            acc[2] += bf2f(q.z); acc[3] += bf2f(q.w);
        }
    } else {
        for (; e + 4 <= e1; e += 4) {
            int s0 = csr_src[e];
            int s1 = csr_src[e + 1];
            int s2 = csr_src[e + 2];
            int s3 = csr_src[e + 3];
            ushort2 q0 = *(const ushort2*)(Vl + (size_t)s0 * W);
            ushort2 q1 = *(const ushort2*)(Vl + (size_t)s1 * W);
            ushort2 q2 = *(const ushort2*)(Vl + (size_t)s2 * W);
            ushort2 q3 = *(const ushort2*)(Vl + (size_t)s3 * W);
            acc[0] += (bf2f(q0.x) + bf2f(q1.x)) + (bf2f(q2.x) + bf2f(q3.x));
            acc[1] += (bf2f(q0.y) + bf2f(q1.y)) + (bf2f(q2.y) + bf2f(q3.y));
        }
        for (; e < e1; e++) {
            int s = csr_src[e];
            ushort2 q = *(const ushort2*)(Vl + (size_t)s * W);
            acc[0] += bf2f(q.x); acc[1] += bf2f(q.y);
        }
    }

    float part[VEC];
    #pragma unroll
    for (int c = 0; c < VEC; c++) part[c] = __shfl(acc[c], (lane + 32) & 63, 64);

    if (lane < 32) {
        float nd = norm_d[wid];
        float res[VEC];
        #pragma unroll
        for (int c = 0; c < VEC; c++) {
            float r = nd * acc[c] + part[c] + bias[lane * VEC + c];
            if (RELU) r = fmaxf(r, 0.f);
            res[c] = r;
        }
        if constexpr (OUT_BF16) {
            unsigned short* po = (unsigned short*)outv + (size_t)wid * (32 * VEC) + lane * VEC;
            if constexpr (VEC == 4) {
                ushort4 o;
                o.x = f2bf(res[0]); o.y = f2bf(res[1]);
                o.z = f2bf(res[2]); o.w = f2bf(res[3]);
                *(ushort4*)po = o;
            } else {
                ushort2 o; o.x = f2bf(res[0]); o.y = f2bf(res[1]);
                *(ushort2*)po = o;
            }
        } else {
            float* po = (float*)outv + (size_t)wid * (32 * VEC) + lane * VEC;
            if constexpr (VEC == 4) {
                float4 o; o.x = res[0]; o.y = res[1]; o.z = res[2]; o.w = res[3];
                *(float4*)po = o;
            } else {
                float2 o; o.x = res[0]; o.y = res[1];
                *(float2*)po = o;
            }
        }
    }
}

// ---------------- launch ----------------

extern "C" void kernel_launch(void* const* d_in, const int* in_sizes, int n_in,
                              void* d_out, int out_size, void* d_ws, size_t ws_size,
                              hipStream_t stream) {
    const float* raw_x  = (const float*)d_in[0];
    const int*   src    = (const int*)d_in[1];
    const int*   dst    = (const int*)d_in[2];
    const float* gc_w0  = (const float*)d_in[3];
    const float* gc_b0  = (const float*)d_in[4];
    const float* gc_w1  = (const float*)d_in[5];
    const float* gc_b1  = (const float*)d_in[6];
    const float* gc_w2  = (const float*)d_in[7];
    const float* gc_b2  = (const float*)d_in[8];
    const float* res_w0 = (const float*)d_in[9];
    const float* res_w1 = (const float*)d_in[10];
    const float* res_w2 = (const float*)d_in[11];

    const int n  = in_sizes[0] / NFEAT;   // 100000
    const int ne = in_sizes[1];           // 1600000
    float* out = (float*)d_out;

    // workspace layout (all bf16 activations)
    char* w = (char*)d_ws;
    unsigned short* V   = (unsigned short*)w; w += (size_t)n * 256 * sizeof(unsigned short); // 51.2 MB
    unsigned short* Xb  = (unsigned short*)w; w += (size_t)n * 128 * sizeof(unsigned short); // 25.6 MB
    unsigned short* X1b = (unsigned short*)w; w += (size_t)n * 128 * sizeof(unsigned short); // 25.6 MB
    float* norm_s = (float*)w;   w += (size_t)n * sizeof(float);
    float* norm_d = (float*)w;   w += (size_t)n * sizeof(float);
    int* out_cnt = (int*)w;      w += (size_t)n * sizeof(int);
    int* in_cnt = (int*)w;       w += (size_t)n * sizeof(int);
    int* row_ptr = (int*)w;      w += (size_t)(n + 1) * sizeof(int);
    int* cursor = (int*)w;       w += (size_t)n * sizeof(int);
    int* bsums = (int*)w;        w += 4096;
    int* csr_src = (int*)w;      w += (size_t)ne * sizeof(int);

    const int nb = (n + 1023) / 1024;

    // --- preprocessing: bf16 cast, degrees, norms, CSR-by-dst ---
    cast_bf16_kernel<<<(n * (NFEAT / 4) + 255) / 256, 256, 0, stream>>>(raw_x, Xb, n * (NFEAT / 4));
    zero_ints<<<(2 * n + 255) / 256, 256, 0, stream>>>(out_cnt, 2 * n); // out_cnt & in_cnt contiguous
    degree_kernel<<<(ne + 255) / 256, 256, 0, stream>>>(src, dst, ne, out_cnt, in_cnt);
    norm_kernel<<<(n + 255) / 256, 256, 0, stream>>>(out_cnt, in_cnt, norm_s, norm_d, n);
    scan_phase1<<<nb, 1024, 0, stream>>>(in_cnt, row_ptr, bsums, n);
    scan_phase2<<<1, 1024, 0, stream>>>(bsums, nb);
    scan_phase3<<<nb, 1024, 0, stream>>>(row_ptr, bsums, cursor, n, ne);
    scatter_kernel<<<(ne + 255) / 256, 256, 0, stream>>>(src, dst, ne, cursor, csr_src);

    const dim3 gemm_grid_wide((n + 63) / 64, 4);
    const dim3 gemm_grid_narrow((n + 63) / 64, 2);
    const int spmm_blocks = (n + 3) / 4;

    // --- layer 0: x1 = relu(norm_d*spmm(norm_s*(x@W0)) + spmm(x@R0) + b0) ---
    gemm_kernel<256, 128><<<gemm_grid_wide, 256, 0, stream>>>(Xb, n, gc_w0, res_w0, norm_s, V);
    spmm_kernel<4, true, true><<<spmm_blocks, 256, 0, stream>>>(V, row_ptr, csr_src, norm_d, gc_b0, X1b, n);

    // --- layer 1 ---
    gemm_kernel<256, 128><<<gemm_grid_wide, 256, 0, stream>>>(X1b, n, gc_w1, res_w1, norm_s, V);
    spmm_kernel<4, true, true><<<spmm_blocks, 256, 0, stream>>>(V, row_ptr, csr_src, norm_d, gc_b1, X1b, n);

    // --- layer 2: output 64-wide fp32, no relu ---
    gemm_kernel<128, 64><<<gemm_grid_narrow, 256, 0, stream>>>(X1b, n, gc_w2, res_w2, norm_s, V);
    spmm_kernel<2, false, false><<<spmm_blocks, 256, 0, stream>>>(V, row_ptr, csr_src, norm_d, gc_b2, out, n);
}

// Round 6
// 755.859 us; speedup vs baseline: 10.7558x; 1.2089x over previous
//
#include <hip/hip_runtime.h>
#include <cstdint>
#include <cstddef>

#define NFEAT 128

typedef __attribute__((ext_vector_type(8))) short bf16x8;
typedef __attribute__((ext_vector_type(4))) float f32x4;

// bf16 <-> f32 helpers (RNE, no NaN handling needed — activations are finite)
__device__ __forceinline__ unsigned short f2bf(float x) {
    union { float f; unsigned u; } v; v.f = x;
    unsigned r = v.u + 0x7fffu + ((v.u >> 16) & 1u);
    return (unsigned short)(r >> 16);
}
__device__ __forceinline__ float bf2f(unsigned short b) {
    union { unsigned u; float f; } v; v.u = ((unsigned)b) << 16;
    return v.f;
}

// ---------------- preprocessing kernels ----------------

__global__ void zero_ints(int* __restrict__ p, int n) {
    int i = blockIdx.x * blockDim.x + threadIdx.x;
    if (i < n) p[i] = 0;
}

__global__ void cast_bf16_kernel(const float* __restrict__ x, unsigned short* __restrict__ y, int n4) {
    int i = blockIdx.x * blockDim.x + threadIdx.x;
    if (i < n4) {
        float4 v = ((const float4*)x)[i];
        ushort4 o;
        o.x = f2bf(v.x); o.y = f2bf(v.y); o.z = f2bf(v.z); o.w = f2bf(v.w);
        ((ushort4*)y)[i] = o;
    }
}

// Pack [gcW | resW] (fp32 row-major [128][SPLIT]) into bf16 MFMA B-fragment order:
// Wf[((kb*NT + nt)*64 + lane)*8 + j] = Wcat[kb*32 + (lane>>4)*8 + j][nt*16 + (lane&15)]
template <int NOUT>
__global__ void prep_wf(const float* __restrict__ gcW, const float* __restrict__ resW,
                        unsigned short* __restrict__ Wf) {
    constexpr int NT = NOUT / 16;
    constexpr int SPLIT = NOUT / 2;
    int tid = blockIdx.x * 256 + threadIdx.x;
    if (tid >= 128 * NOUT) return;
    int k = tid / NOUT, n = tid % NOUT;
    float v = (n < SPLIT) ? gcW[k * SPLIT + n] : resW[k * SPLIT + (n - SPLIT)];
    int kb = k >> 5, koff = k & 31, quad = koff >> 3, j = koff & 7;
    int nt = n >> 4, ncol = n & 15, lane = quad * 16 + ncol;
    Wf[((kb * NT + nt) * 64 + lane) * 8 + j] = f2bf(v);
}

__global__ void degree_kernel(const int* __restrict__ src, const int* __restrict__ dst,
                              int ne, int* __restrict__ out_cnt, int* __restrict__ in_cnt) {
    int e = blockIdx.x * blockDim.x + threadIdx.x;
    if (e < ne) {
        atomicAdd(&out_cnt[src[e]], 1);
        atomicAdd(&in_cnt[dst[e]], 1);
    }
}

__global__ void norm_kernel(const int* __restrict__ out_cnt, const int* __restrict__ in_cnt,
                            float* __restrict__ norm_s, float* __restrict__ norm_d, int n) {
    int i = blockIdx.x * blockDim.x + threadIdx.x;
    if (i < n) {
        norm_s[i] = rsqrtf(fmaxf((float)out_cnt[i], 1.0f));
        norm_d[i] = rsqrtf(fmaxf((float)in_cnt[i], 1.0f));
    }
}

// Block-wise exclusive scan (Hillis-Steele), 1024 threads/block.
__global__ void scan_phase1(const int* __restrict__ cnt, int* __restrict__ excl,
                            int* __restrict__ bsums, int n) {
    __shared__ int tmp[1024];
    int tid = threadIdx.x;
    int gid = blockIdx.x * 1024 + tid;
    int v = (gid < n) ? cnt[gid] : 0;
    tmp[tid] = v;
    for (int off = 1; off < 1024; off <<= 1) {
        __syncthreads();
        int t = (tid >= off) ? tmp[tid - off] : 0;
        __syncthreads();
        tmp[tid] += t;
    }
    __syncthreads();
    if (gid < n) excl[gid] = tmp[tid] - v;
    if (tid == 0) bsums[blockIdx.x] = tmp[1023];
}

__global__ void scan_phase2(int* __restrict__ bsums, int nb) {
    __shared__ int tmp[1024];
    int tid = threadIdx.x;
    int v = (tid < nb) ? bsums[tid] : 0;
    tmp[tid] = v;
    for (int off = 1; off < 1024; off <<= 1) {
        __syncthreads();
        int t = (tid >= off) ? tmp[tid - off] : 0;
        __syncthreads();
        tmp[tid] += t;
    }
    __syncthreads();
    if (tid < nb) bsums[tid] = tmp[tid] - v;
}

__global__ void scan_phase3(int* __restrict__ row_ptr, const int* __restrict__ bsums,
                            int* __restrict__ cursor, int n, int ne) {
    int gid = blockIdx.x * 1024 + threadIdx.x;
    if (gid < n) {
        int r = row_ptr[gid] + bsums[blockIdx.x];
        row_ptr[gid] = r;
        cursor[gid] = r;
    }
    if (gid == 0) row_ptr[n] = ne;
}

__global__ void scatter_kernel(const int* __restrict__ src, const int* __restrict__ dst,
                               int ne, int* __restrict__ cursor, int* __restrict__ csr_src) {
    int e = blockIdx.x * blockDim.x + threadIdx.x;
    if (e < ne) {
        int d = dst[e];
        int p = atomicAdd(&cursor[d], 1);
        csr_src[p] = src[e];
    }
}

// ---------------- MFMA dual-GEMM: V = X @ [gcW | resW], gc half scaled by norm_s[row] ----
// X: [M,128] bf16. Wf: fragment-major bf16 (see prep_wf). V: [M,NOUT] bf16.
// Block = 256 thr = 4 waves; wave w computes rows blockIdx.x*64 + w*16, all NOUT cols.
// Per wave: A (16x128) in 4 bf16x8 frags (registers), B from LDS, 4 MFMA per 16-col tile.
// mfma_f32_16x16x32_bf16 layouts (HW-verified m89/m91): A[m=lane&15][k=(lane>>4)*8+j],
// C/D col=lane&15, row=(lane>>4)*4+reg.

template <int NOUT>
__global__ __launch_bounds__(256) void gemm_mfma(
    const unsigned short* __restrict__ X, int M,
    const unsigned short* __restrict__ Wf,
    const float* __restrict__ norm_s, unsigned short* __restrict__ V) {
    constexpr int NT = NOUT / 16;
    constexpr int SPLIT = NOUT / 2;
    __shared__ unsigned short Bs[128 * NOUT];

    const int t = threadIdx.x;
    const int wave = t >> 6, lane = t & 63;
    const int r0 = blockIdx.x * 64 + wave * 16;

    // stage Wf -> LDS (contiguous 16B copies, conflict-free)
    constexpr int TOT16 = 128 * NOUT * 2 / 16;
    const uint4* gsrc = (const uint4*)Wf;
    uint4* ldst = (uint4*)Bs;
    for (int i = t; i < TOT16; i += 256) ldst[i] = gsrc[i];

    // A fragments from global (rows am = r0 + (lane&15), k = kb*32 + (lane>>4)*8 + j)
    const int am = r0 + (lane & 15);
    const int kq = (lane >> 4) * 8;
    bf16x8 afrag[4];
    if (am < M) {
        const unsigned short* ap = X + (size_t)am * NFEAT + kq;
        #pragma unroll
        for (int kb = 0; kb < 4; kb++)
            afrag[kb] = *(const bf16x8*)(ap + kb * 32);
    } else {
        #pragma unroll
        for (int kb = 0; kb < 4; kb++) afrag[kb] = bf16x8{};
    }

    // per-lane norm_s for the 4 output rows this lane owns (row = (lane>>4)*4 + reg)
    const int orow = r0 + (lane >> 4) * 4;
    float ns[4];
    #pragma unroll
    for (int r = 0; r < 4; r++)
        ns[r] = (orow + r < M) ? norm_s[orow + r] : 0.f;

    __syncthreads();

    #pragma unroll 1
    for (int nt = 0; nt < NT; nt++) {
        f32x4 acc = {0.f, 0.f, 0.f, 0.f};
        #pragma unroll
        for (int kb = 0; kb < 4; kb++) {
            bf16x8 b = *(const bf16x8*)(Bs + ((kb * NT + nt) * 64 + lane) * 8);
            acc = __builtin_amdgcn_mfma_f32_16x16x32_bf16(afrag[kb], b, acc, 0, 0, 0);
        }
        const int gcol = nt * 16 + (lane & 15);
        const bool isGc = gcol < SPLIT;
        #pragma unroll
        for (int r = 0; r < 4; r++) {
            int gm = orow + r;
            if (gm < M) {
                float v = acc[r] * (isGc ? ns[r] : 1.0f);
                V[(size_t)gm * NOUT + gcol] = f2bf(v);
            }
        }
    }
}

// ---------------- pull-mode SpMM + epilogue ----------------
// One wave per node. V row = 64*VEC bf16. Lanes 0..31 gc half, 32..63 residual half.
// Edge loop unrolled x4 with batched independent gathers (round-4: latency-bound fix).
// out[node] = relu? ( norm_d[node]*Agg_gc + Agg_res + bias ); fp32 accumulation.

template <int VEC, bool RELU, bool OUT_BF16>
__global__ __launch_bounds__(256) void spmm_kernel(
    const unsigned short* __restrict__ V, const int* __restrict__ row_ptr,
    const int* __restrict__ csr_src, const float* __restrict__ norm_d,
    const float* __restrict__ bias, void* __restrict__ outv, int n) {
    int wid = (blockIdx.x * 256 + threadIdx.x) >> 6;
    int lane = threadIdx.x & 63;
    if (wid >= n) return;

    constexpr int W = 64 * VEC;
    float acc[VEC];
    #pragma unroll
    for (int c = 0; c < VEC; c++) acc[c] = 0.f;

    const int e0 = row_ptr[wid];
    const int e1 = row_ptr[wid + 1];
    const unsigned short* Vl = V + (size_t)lane * VEC;

    int e = e0;
    if constexpr (VEC == 4) {
        for (; e + 4 <= e1; e += 4) {
            int s0 = csr_src[e];
            int s1 = csr_src[e + 1];
            int s2 = csr_src[e + 2];
            int s3 = csr_src[e + 3];
            ushort4 q0 = *(const ushort4*)(Vl + (size_t)s0 * W);
            ushort4 q1 = *(const ushort4*)(Vl + (size_t)s1 * W);
            ushort4 q2 = *(const ushort4*)(Vl + (size_t)s2 * W);
            ushort4 q3 = *(const ushort4*)(Vl + (size_t)s3 * W);
            acc[0] += (bf2f(q0.x) + bf2f(q1.x)) + (bf2f(q2.x) + bf2f(q3.x));
            acc[1] += (bf2f(q0.y) + bf2f(q1.y)) + (bf2f(q2.y) + bf2f(q3.y));
            acc[2] += (bf2f(q0.z) + bf2f(q1.z)) + (bf2f(q2.z) + bf2f(q3.z));
            acc[3] += (bf2f(q0.w) + bf2f(q1.w)) + (bf2f(q2.w) + bf2f(q3.w));
        }
        for (; e < e1; e++) {
            int s = csr_src[e];
            ushort4 q = *(const ushort4*)(Vl + (size_t)s * W);
            acc[0] += bf2f(q.x); acc[1] += bf2f(q.y);
            acc[2] += bf2f(q.z); acc[3] += bf2f(q.w);
        }
    } else {
        for (; e + 4 <= e1; e += 4) {
            int s0 = csr_src[e];
            int s1 = csr_src[e + 1];
            int s2 = csr_src[e + 2];
            int s3 = csr_src[e + 3];
            ushort2 q0 = *(const ushort2*)(Vl + (size_t)s0 * W);
            ushort2 q1 = *(const ushort2*)(Vl + (size_t)s1 * W);
            ushort2 q2 = *(const ushort2*)(Vl + (size_t)s2 * W);
            ushort2 q3 = *(const ushort2*)(Vl + (size_t)s3 * W);
            acc[0] += (bf2f(q0.x) + bf2f(q1.x)) + (bf2f(q2.x) + bf2f(q3.x));
            acc[1] += (bf2f(q0.y) + bf2f(q1.y)) + (bf2f(q2.y) + bf2f(q3.y));
        }
        for (; e < e1; e++) {
            int s = csr_src[e];
            ushort2 q = *(const ushort2*)(Vl + (size_t)s * W);
            acc[0] += bf2f(q.x); acc[1] += bf2f(q.y);
        }
    }

    float part[VEC];
    #pragma unroll
    for (int c = 0; c < VEC; c++) part[c] = __shfl(acc[c], (lane + 32) & 63, 64);

    if (lane < 32) {
        float nd = norm_d[wid];
        float res[VEC];
        #pragma unroll
        for (int c = 0; c < VEC; c++) {
            float r = nd * acc[c] + part[c] + bias[lane * VEC + c];
            if (RELU) r = fmaxf(r, 0.f);
            res[c] = r;
        }
        if constexpr (OUT_BF16) {
            unsigned short* po = (unsigned short*)outv + (size_t)wid * (32 * VEC) + lane * VEC;
            if constexpr (VEC == 4) {
                ushort4 o;
                o.x = f2bf(res[0]); o.y = f2bf(res[1]);
                o.z = f2bf(res[2]); o.w = f2bf(res[3]);
                *(ushort4*)po = o;
            } else {
                ushort2 o; o.x = f2bf(res[0]); o.y = f2bf(res[1]);
                *(ushort2*)po = o;
            }
        } else {
            float* po = (float*)outv + (size_t)wid * (32 * VEC) + lane * VEC;
            if constexpr (VEC == 4) {
                float4 o; o.x = res[0]; o.y = res[1]; o.z = res[2]; o.w = res[3];
                *(float4*)po = o;
            } else {
                float2 o; o.x = res[0]; o.y = res[1];
                *(float2*)po = o;
            }
        }
    }
}

// ---------------- launch ----------------

extern "C" void kernel_launch(void* const* d_in, const int* in_sizes, int n_in,
                              void* d_out, int out_size, void* d_ws, size_t ws_size,
                              hipStream_t stream) {
    const float* raw_x  = (const float*)d_in[0];
    const int*   src    = (const int*)d_in[1];
    const int*   dst    = (const int*)d_in[2];
    const float* gc_w0  = (const float*)d_in[3];
    const float* gc_b0  = (const float*)d_in[4];
    const float* gc_w1  = (const float*)d_in[5];
    const float* gc_b1  = (const float*)d_in[6];
    const float* gc_w2  = (const float*)d_in[7];
    const float* gc_b2  = (const float*)d_in[8];
    const float* res_w0 = (const float*)d_in[9];
    const float* res_w1 = (const float*)d_in[10];
    const float* res_w2 = (const float*)d_in[11];

    const int n  = in_sizes[0] / NFEAT;   // 100000
    const int ne = in_sizes[1];           // 1600000
    float* out = (float*)d_out;

    // workspace layout (all bf16 activations)
    char* w = (char*)d_ws;
    unsigned short* V   = (unsigned short*)w; w += (size_t)n * 256 * sizeof(unsigned short); // 51.2 MB
    unsigned short* Xb  = (unsigned short*)w; w += (size_t)n * 128 * sizeof(unsigned short); // 25.6 MB
    unsigned short* X1b = (unsigned short*)w; w += (size_t)n * 128 * sizeof(unsigned short); // 25.6 MB
    float* norm_s = (float*)w;   w += (size_t)n * sizeof(float);
    float* norm_d = (float*)w;   w += (size_t)n * sizeof(float);
    int* out_cnt = (int*)w;      w += (size_t)n * sizeof(int);
    int* in_cnt = (int*)w;       w += (size_t)n * sizeof(int);
    int* row_ptr = (int*)w;      w += (size_t)(n + 1) * sizeof(int);
    int* cursor = (int*)w;       w += (size_t)n * sizeof(int);
    int* bsums = (int*)w;        w += 4096;
    int* csr_src = (int*)w;      w += (size_t)ne * sizeof(int);
    unsigned short* Wf0 = (unsigned short*)w; w += 128 * 256 * sizeof(unsigned short);
    unsigned short* Wf1 = (unsigned short*)w; w += 128 * 256 * sizeof(unsigned short);
    unsigned short* Wf2 = (unsigned short*)w; w += 128 * 128 * sizeof(unsigned short);

    const int nb = (n + 1023) / 1024;

    // --- preprocessing: bf16 cast, weight fragments, degrees, norms, CSR-by-dst ---
    cast_bf16_kernel<<<(n * (NFEAT / 4) + 255) / 256, 256, 0, stream>>>(raw_x, Xb, n * (NFEAT / 4));
    prep_wf<256><<<128, 256, 0, stream>>>(gc_w0, res_w0, Wf0);
    prep_wf<256><<<128, 256, 0, stream>>>(gc_w1, res_w1, Wf1);
    prep_wf<128><<<64, 256, 0, stream>>>(gc_w2, res_w2, Wf2);
    zero_ints<<<(2 * n + 255) / 256, 256, 0, stream>>>(out_cnt, 2 * n); // out_cnt & in_cnt contiguous
    degree_kernel<<<(ne + 255) / 256, 256, 0, stream>>>(src, dst, ne, out_cnt, in_cnt);
    norm_kernel<<<(n + 255) / 256, 256, 0, stream>>>(out_cnt, in_cnt, norm_s, norm_d, n);
    scan_phase1<<<nb, 1024, 0, stream>>>(in_cnt, row_ptr, bsums, n);
    scan_phase2<<<1, 1024, 0, stream>>>(bsums, nb);
    scan_phase3<<<nb, 1024, 0, stream>>>(row_ptr, bsums, cursor, n, ne);
    scatter_kernel<<<(ne + 255) / 256, 256, 0, stream>>>(src, dst, ne, cursor, csr_src);

    const int gemm_blocks = (n + 63) / 64;
    const int spmm_blocks = (n + 3) / 4;

    // --- layer 0: x1 = relu(norm_d*spmm(norm_s*(x@W0)) + spmm(x@R0) + b0) ---
    gemm_mfma<256><<<gemm_blocks, 256, 0, stream>>>(Xb, n, Wf0, norm_s, V);
    spmm_kernel<4, true, true><<<spmm_blocks, 256, 0, stream>>>(V, row_ptr, csr_src, norm_d, gc_b0, X1b, n);

    // --- layer 1 ---
    gemm_mfma<256><<<gemm_blocks, 256, 0, stream>>>(X1b, n, Wf1, norm_s, V);
    spmm_kernel<4, true, true><<<spmm_blocks, 256, 0, stream>>>(V, row_ptr, csr_src, norm_d, gc_b1, X1b, n);

    // --- layer 2: output 64-wide fp32, no relu ---
    gemm_mfma<128><<<gemm_blocks, 256, 0, stream>>>(X1b, n, Wf2, norm_s, V);
    spmm_kernel<2, false, false><<<spmm_blocks, 256, 0, stream>>>(V, row_ptr, csr_src, norm_d, gc_b2, out, n);
}

// Round 7
// 676.358 us; speedup vs baseline: 12.0200x; 1.1175x over previous
//
#include <hip/hip_runtime.h>
#include <cstdint>
#include <cstddef>

#define NFEAT 128
#define KBUCK 1024

typedef __attribute__((ext_vector_type(8))) short bf16x8;
typedef __attribute__((ext_vector_type(4))) float f32x4;

// bf16 <-> f32 helpers (RNE, no NaN handling needed — activations are finite)
__device__ __forceinline__ unsigned short f2bf(float x) {
    union { float f; unsigned u; } v; v.f = x;
    unsigned r = v.u + 0x7fffu + ((v.u >> 16) & 1u);
    return (unsigned short)(r >> 16);
}
__device__ __forceinline__ float bf2f(unsigned short b) {
    union { unsigned u; float f; } v; v.u = ((unsigned)b) << 16;
    return v.f;
}

// ---------------- preprocessing kernels ----------------

__global__ void zero_ints(int* __restrict__ p, int n) {
    int i = blockIdx.x * blockDim.x + threadIdx.x;
    if (i < n) p[i] = 0;
}

__global__ void cast_bf16_kernel(const float* __restrict__ x, unsigned short* __restrict__ y, int n4) {
    int i = blockIdx.x * blockDim.x + threadIdx.x;
    if (i < n4) {
        float4 v = ((const float4*)x)[i];
        ushort4 o;
        o.x = f2bf(v.x); o.y = f2bf(v.y); o.z = f2bf(v.z); o.w = f2bf(v.w);
        ((ushort4*)y)[i] = o;
    }
}

// Pack [gcW | resW] (fp32 row-major [128][SPLIT]) into bf16 MFMA B-fragment order:
// Wf[((kb*NT + nt)*64 + lane)*8 + j] = Wcat[kb*32 + (lane>>4)*8 + j][nt*16 + (lane&15)]
template <int NOUT>
__global__ void prep_wf(const float* __restrict__ gcW, const float* __restrict__ resW,
                        unsigned short* __restrict__ Wf) {
    constexpr int NT = NOUT / 16;
    constexpr int SPLIT = NOUT / 2;
    int tid = blockIdx.x * 256 + threadIdx.x;
    if (tid >= 128 * NOUT) return;
    int k = tid / NOUT, n = tid % NOUT;
    float v = (n < SPLIT) ? gcW[k * SPLIT + n] : resW[k * SPLIT + (n - SPLIT)];
    int kb = k >> 5, koff = k & 31, quad = koff >> 3, j = koff & 7;
    int nt = n >> 4, ncol = n & 15, lane = quad * 16 + ncol;
    Wf[((kb * NT + nt) * 64 + lane) * 8 + j] = f2bf(v);
}

__global__ void degree_kernel(const int* __restrict__ src, const int* __restrict__ dst,
                              int ne, int* __restrict__ out_cnt, int* __restrict__ in_cnt) {
    int e = blockIdx.x * blockDim.x + threadIdx.x;
    if (e < ne) {
        atomicAdd(&out_cnt[src[e]], 1);
        atomicAdd(&in_cnt[dst[e]], 1);
    }
}

__global__ void norm_kernel(const int* __restrict__ out_cnt, const int* __restrict__ in_cnt,
                            float* __restrict__ norm_s, float* __restrict__ norm_d, int n) {
    int i = blockIdx.x * blockDim.x + threadIdx.x;
    if (i < n) {
        norm_s[i] = rsqrtf(fmaxf((float)out_cnt[i], 1.0f));
        norm_d[i] = rsqrtf(fmaxf((float)in_cnt[i], 1.0f));
    }
}

// Block-wise exclusive scan (Hillis-Steele), 1024 threads/block.
__global__ void scan_phase1(const int* __restrict__ cnt, int* __restrict__ excl,
                            int* __restrict__ bsums, int n) {
    __shared__ int tmp[1024];
    int tid = threadIdx.x;
    int gid = blockIdx.x * 1024 + tid;
    int v = (gid < n) ? cnt[gid] : 0;
    tmp[tid] = v;
    for (int off = 1; off < 1024; off <<= 1) {
        __syncthreads();
        int t = (tid >= off) ? tmp[tid - off] : 0;
        __syncthreads();
        tmp[tid] += t;
    }
    __syncthreads();
    if (gid < n) excl[gid] = tmp[tid] - v;
    if (tid == 0) bsums[blockIdx.x] = tmp[1023];
}

__global__ void scan_phase2(int* __restrict__ bsums, int nb) {
    __shared__ int tmp[1024];
    int tid = threadIdx.x;
    int v = (tid < nb) ? bsums[tid] : 0;
    tmp[tid] = v;
    for (int off = 1; off < 1024; off <<= 1) {
        __syncthreads();
        int t = (tid >= off) ? tmp[tid - off] : 0;
        __syncthreads();
        tmp[tid] += t;
    }
    __syncthreads();
    if (tid < nb) bsums[tid] = tmp[tid] - v;
}

__global__ void scan_phase3(int* __restrict__ row_ptr, const int* __restrict__ bsums,
                            int n, int ne) {
    int gid = blockIdx.x * 1024 + threadIdx.x;
    if (gid < n) row_ptr[gid] += bsums[blockIdx.x];
    if (gid == 0) row_ptr[n] = ne;
}

// ---------------- bucketed CSR build (replaces one-shot atomic scatter) ----------------
// Round-6 profile: scatter_kernel 133 us, WRITE_SIZE 105 MB for a 6.4 MB logical CSR
// (16x partial-line amplification; per-edge device-scope atomics). Fix: radix-partition
// edges by dst-range into KBUCK buckets whose ebuf regions coincide with the final CSR
// regions (bucket b starts at row_ptr[b*D]); then build each bucket's CSR slice with one
// block using LDS rank counters — all writes to a line come from one block, no amplification.

__global__ void init_buckets(const int* __restrict__ row_ptr, int* __restrict__ bucket_cursor,
                             int n, int D) {
    int b = blockIdx.x * blockDim.x + threadIdx.x;
    if (b < KBUCK) {
        int d = b * D; if (d > n) d = n;
        bucket_cursor[b] = row_ptr[d];
    }
}

// Phase A: tile = 256*16 = 4096 edges/block. LDS histogram -> one global atomic per
// (block,bucket) to reserve space -> bucket-contiguous (src,dst) writes to ebuf.
__global__ __launch_bounds__(256) void partition_kernel(
    const int* __restrict__ src, const int* __restrict__ dst, int ne, int D,
    int* __restrict__ bucket_cursor, uint2* __restrict__ ebuf) {
    __shared__ int hist[KBUCK];
    __shared__ int gbase[KBUCK];
    const int t = threadIdx.x;
    const int tile0 = blockIdx.x * 4096;

    for (int i = t; i < KBUCK; i += 256) hist[i] = 0;
    __syncthreads();

    int s[16], d[16], r[16];
    #pragma unroll
    for (int j = 0; j < 16; j++) {
        int e = tile0 + j * 256 + t;
        if (e < ne) {
            s[j] = src[e];
            d[j] = dst[e];
            int b = (int)((unsigned)d[j] / (unsigned)D);
            r[j] = atomicAdd(&hist[b], 1);
        }
    }
    __syncthreads();
    for (int i = t; i < KBUCK; i += 256) {
        int c = hist[i];
        gbase[i] = c ? atomicAdd(&bucket_cursor[i], c) : 0;
    }
    __syncthreads();
    #pragma unroll
    for (int j = 0; j < 16; j++) {
        int e = tile0 + j * 256 + t;
        if (e < ne) {
            int b = (int)((unsigned)d[j] / (unsigned)D);
            ebuf[gbase[b] + r[j]] = make_uint2((unsigned)s[j], (unsigned)d[j]);
        }
    }
}

// Phase B: one block per bucket; LDS rank counters; writes confined to this bucket's
// csr slice (~6 KB) -> single-L2 full-line writebacks.
__global__ __launch_bounds__(256) void csr_build_kernel(
    const uint2* __restrict__ ebuf, const int* __restrict__ row_ptr,
    int n, int D, int* __restrict__ csr_src) {
    __shared__ int cnt[256];   // D <= 256 assumed (D = ceil(n/KBUCK) = 98 here)
    const int b = blockIdx.x;
    const int d_lo = b * D;
    if (d_lo >= n) return;
    const int d_hi = (d_lo + D < n) ? d_lo + D : n;
    const int e0 = row_ptr[d_lo], e1 = row_ptr[d_hi];
    for (int i = threadIdx.x; i < D; i += 256) cnt[i] = 0;
    __syncthreads();
    for (int i = e0 + threadIdx.x; i < e1; i += 256) {
        uint2 ed = ebuf[i];
        int dd = (int)ed.y;
        int r = atomicAdd(&cnt[dd - d_lo], 1);
        csr_src[row_ptr[dd] + r] = (int)ed.x;
    }
}

// ---------------- MFMA dual-GEMM: V = X @ [gcW | resW], gc half scaled by norm_s[row] ----
// X: [M,128] bf16. Wf: fragment-major bf16 (see prep_wf). V: [M,NOUT] bf16.
// Block = 256 thr = 4 waves; wave w computes rows blockIdx.x*64 + w*16, all NOUT cols.
// mfma_f32_16x16x32_bf16 layouts (HW-verified m89/m91): A[m=lane&15][k=(lane>>4)*8+j],
// C/D col=lane&15, row=(lane>>4)*4+reg.

template <int NOUT>
__global__ __launch_bounds__(256) void gemm_mfma(
    const unsigned short* __restrict__ X, int M,
    const unsigned short* __restrict__ Wf,
    const float* __restrict__ norm_s, unsigned short* __restrict__ V) {
    constexpr int NT = NOUT / 16;
    constexpr int SPLIT = NOUT / 2;
    __shared__ unsigned short Bs[128 * NOUT];

    const int t = threadIdx.x;
    const int wave = t >> 6, lane = t & 63;
    const int r0 = blockIdx.x * 64 + wave * 16;

    // stage Wf -> LDS (contiguous 16B copies, conflict-free)
    constexpr int TOT16 = 128 * NOUT * 2 / 16;
    const uint4* gsrc = (const uint4*)Wf;
    uint4* ldst = (uint4*)Bs;
    for (int i = t; i < TOT16; i += 256) ldst[i] = gsrc[i];

    // A fragments from global (rows am = r0 + (lane&15), k = kb*32 + (lane>>4)*8 + j)
    const int am = r0 + (lane & 15);
    const int kq = (lane >> 4) * 8;
    bf16x8 afrag[4];
    if (am < M) {
        const unsigned short* ap = X + (size_t)am * NFEAT + kq;
        #pragma unroll
        for (int kb = 0; kb < 4; kb++)
            afrag[kb] = *(const bf16x8*)(ap + kb * 32);
    } else {
        #pragma unroll
        for (int kb = 0; kb < 4; kb++) afrag[kb] = bf16x8{};
    }

    // per-lane norm_s for the 4 output rows this lane owns (row = (lane>>4)*4 + reg)
    const int orow = r0 + (lane >> 4) * 4;
    float ns[4];
    #pragma unroll
    for (int r = 0; r < 4; r++)
        ns[r] = (orow + r < M) ? norm_s[orow + r] : 0.f;

    __syncthreads();

    #pragma unroll 1
    for (int nt = 0; nt < NT; nt++) {
        f32x4 acc = {0.f, 0.f, 0.f, 0.f};
        #pragma unroll
        for (int kb = 0; kb < 4; kb++) {
            bf16x8 b = *(const bf16x8*)(Bs + ((kb * NT + nt) * 64 + lane) * 8);
            acc = __builtin_amdgcn_mfma_f32_16x16x32_bf16(afrag[kb], b, acc, 0, 0, 0);
        }
        const int gcol = nt * 16 + (lane & 15);
        const bool isGc = gcol < SPLIT;
        #pragma unroll
        for (int r = 0; r < 4; r++) {
            int gm = orow + r;
            if (gm < M) {
                float v = acc[r] * (isGc ? ns[r] : 1.0f);
                V[(size_t)gm * NOUT + gcol] = f2bf(v);
            }
        }
    }
}

// ---------------- pull-mode SpMM + epilogue ----------------
// One wave per node. V row = 64*VEC bf16. Lanes 0..31 gc half, 32..63 residual half.
// Edge loop unrolled x4 with batched independent gathers (round-4: latency-bound fix).
// out[node] = relu? ( norm_d[node]*Agg_gc + Agg_res + bias ); fp32 accumulation.

template <int VEC, bool RELU, bool OUT_BF16>
__global__ __launch_bounds__(256) void spmm_kernel(
    const unsigned short* __restrict__ V, const int* __restrict__ row_ptr,
    const int* __restrict__ csr_src, const float* __restrict__ norm_d,
    const float* __restrict__ bias, void* __restrict__ outv, int n) {
    int wid = (blockIdx.x * 256 + threadIdx.x) >> 6;
    int lane = threadIdx.x & 63;
    if (wid >= n) return;

    constexpr int W = 64 * VEC;
    float acc[VEC];
    #pragma unroll
    for (int c = 0; c < VEC; c++) acc[c] = 0.f;

    const int e0 = row_ptr[wid];
    const int e1 = row_ptr[wid + 1];
    const unsigned short* Vl = V + (size_t)lane * VEC;

    int e = e0;
    if constexpr (VEC == 4) {
        for (; e + 4 <= e1; e += 4) {
            int s0 = csr_src[e];
            int s1 = csr_src[e + 1];
            int s2 = csr_src[e + 2];
            int s3 = csr_src[e + 3];
            ushort4 q0 = *(const ushort4*)(Vl + (size_t)s0 * W);
            ushort4 q1 = *(const ushort4*)(Vl + (size_t)s1 * W);
            ushort4 q2 = *(const ushort4*)(Vl + (size_t)s2 * W);
            ushort4 q3 = *(const ushort4*)(Vl + (size_t)s3 * W);
            acc[0] += (bf2f(q0.x) + bf2f(q1.x)) + (bf2f(q2.x) + bf2f(q3.x));
            acc[1] += (bf2f(q0.y) + bf2f(q1.y)) + (bf2f(q2.y) + bf2f(q3.y));
            acc[2] += (bf2f(q0.z) + bf2f(q1.z)) + (bf2f(q2.z) + bf2f(q3.z));
            acc[3] += (bf2f(q0.w) + bf2f(q1.w)) + (bf2f(q2.w) + bf2f(q3.w));
        }
        for (; e < e1; e++) {
            int s = csr_src[e];
            ushort4 q = *(const ushort4*)(Vl + (size_t)s * W);
            acc[0] += bf2f(q.x); acc[1] += bf2f(q.y);
            acc[2] += bf2f(q.z); acc[3] += bf2f(q.w);
        }
    } else {
        for (; e + 4 <= e1; e += 4) {
            int s0 = csr_src[e];
            int s1 = csr_src[e + 1];
            int s2 = csr_src[e + 2];
            int s3 = csr_src[e + 3];
            ushort2 q0 = *(const ushort2*)(Vl + (size_t)s0 * W);
            ushort2 q1 = *(const ushort2*)(Vl + (size_t)s1 * W);
            ushort2 q2 = *(const ushort2*)(Vl + (size_t)s2 * W);
            ushort2 q3 = *(const ushort2*)(Vl + (size_t)s3 * W);
            acc[0] += (bf2f(q0.x) + bf2f(q1.x)) + (bf2f(q2.x) + bf2f(q3.x));
            acc[1] += (bf2f(q0.y) + bf2f(q1.y)) + (bf2f(q2.y) + bf2f(q3.y));
        }
        for (; e < e1; e++) {
            int s = csr_src[e];
            ushort2 q = *(const ushort2*)(Vl + (size_t)s * W);
            acc[0] += bf2f(q.x); acc[1] += bf2f(q.y);
        }
    }

    float part[VEC];
    #pragma unroll
    for (int c = 0; c < VEC; c++) part[c] = __shfl(acc[c], (lane + 32) & 63, 64);

    if (lane < 32) {
        float nd = norm_d[wid];
        float res[VEC];
        #pragma unroll
        for (int c = 0; c < VEC; c++) {
            float r = nd * acc[c] + part[c] + bias[lane * VEC + c];
            if (RELU) r = fmaxf(r, 0.f);
            res[c] = r;
        }
        if constexpr (OUT_BF16) {
            unsigned short* po = (unsigned short*)outv + (size_t)wid * (32 * VEC) + lane * VEC;
            if constexpr (VEC == 4) {
                ushort4 o;
                o.x = f2bf(res[0]); o.y = f2bf(res[1]);
                o.z = f2bf(res[2]); o.w = f2bf(res[3]);
                *(ushort4*)po = o;
            } else {
                ushort2 o; o.x = f2bf(res[0]); o.y = f2bf(res[1]);
                *(ushort2*)po = o;
            }
        } else {
            float* po = (float*)outv + (size_t)wid * (32 * VEC) + lane * VEC;
            if constexpr (VEC == 4) {
                float4 o; o.x = res[0]; o.y = res[1]; o.z = res[2]; o.w = res[3];
                *(float4*)po = o;
            } else {
                float2 o; o.x = res[0]; o.y = res[1];
                *(float2*)po = o;
            }
        }
    }
}

// ---------------- launch ----------------

extern "C" void kernel_launch(void* const* d_in, const int* in_sizes, int n_in,
                              void* d_out, int out_size, void* d_ws, size_t ws_size,
                              hipStream_t stream) {
    const float* raw_x  = (const float*)d_in[0];
    const int*   src    = (const int*)d_in[1];
    const int*   dst    = (const int*)d_in[2];
    const float* gc_w0  = (const float*)d_in[3];
    const float* gc_b0  = (const float*)d_in[4];
    const float* gc_w1  = (const float*)d_in[5];
    const float* gc_b1  = (const float*)d_in[6];
    const float* gc_w2  = (const float*)d_in[7];
    const float* gc_b2  = (const float*)d_in[8];
    const float* res_w0 = (const float*)d_in[9];
    const float* res_w1 = (const float*)d_in[10];
    const float* res_w2 = (const float*)d_in[11];

    const int n  = in_sizes[0] / NFEAT;   // 100000
    const int ne = in_sizes[1];           // 1600000
    float* out = (float*)d_out;
    const int D = (n + KBUCK - 1) / KBUCK;   // dsts per bucket (98)

    // workspace layout (all bf16 activations)
    char* w = (char*)d_ws;
    unsigned short* V   = (unsigned short*)w; w += (size_t)n * 256 * sizeof(unsigned short); // 51.2 MB
    unsigned short* Xb  = (unsigned short*)w; w += (size_t)n * 128 * sizeof(unsigned short); // 25.6 MB
    unsigned short* X1b = (unsigned short*)w; w += (size_t)n * 128 * sizeof(unsigned short); // 25.6 MB
    float* norm_s = (float*)w;   w += (size_t)n * sizeof(float);
    float* norm_d = (float*)w;   w += (size_t)n * sizeof(float);
    int* out_cnt = (int*)w;      w += (size_t)n * sizeof(int);
    int* in_cnt = (int*)w;       w += (size_t)n * sizeof(int);
    int* row_ptr = (int*)w;      w += (size_t)(n + 1) * sizeof(int);
    int* bucket_cursor = (int*)w; w += KBUCK * sizeof(int);
    int* bsums = (int*)w;        w += 4096;
    int* csr_src = (int*)w;      w += (size_t)ne * sizeof(int);
    uint2* ebuf = (uint2*)w;     w += (size_t)ne * sizeof(uint2);       // 12.8 MB
    unsigned short* Wf0 = (unsigned short*)w; w += 128 * 256 * sizeof(unsigned short);
    unsigned short* Wf1 = (unsigned short*)w; w += 128 * 256 * sizeof(unsigned short);
    unsigned short* Wf2 = (unsigned short*)w; w += 128 * 128 * sizeof(unsigned short);

    const int nb = (n + 1023) / 1024;

    // --- preprocessing: bf16 cast, weight fragments, degrees, norms, bucketed CSR ---
    cast_bf16_kernel<<<(n * (NFEAT / 4) + 255) / 256, 256, 0, stream>>>(raw_x, Xb, n * (NFEAT / 4));
    prep_wf<256><<<128, 256, 0, stream>>>(gc_w0, res_w0, Wf0);
    prep_wf<256><<<128, 256, 0, stream>>>(gc_w1, res_w1, Wf1);
    prep_wf<128><<<64, 256, 0, stream>>>(gc_w2, res_w2, Wf2);
    zero_ints<<<(2 * n + 255) / 256, 256, 0, stream>>>(out_cnt, 2 * n); // out_cnt & in_cnt contiguous
    degree_kernel<<<(ne + 255) / 256, 256, 0, stream>>>(src, dst, ne, out_cnt, in_cnt);
    norm_kernel<<<(n + 255) / 256, 256, 0, stream>>>(out_cnt, in_cnt, norm_s, norm_d, n);
    scan_phase1<<<nb, 1024, 0, stream>>>(in_cnt, row_ptr, bsums, n);
    scan_phase2<<<1, 1024, 0, stream>>>(bsums, nb);
    scan_phase3<<<nb, 1024, 0, stream>>>(row_ptr, bsums, n, ne);
    init_buckets<<<(KBUCK + 255) / 256, 256, 0, stream>>>(row_ptr, bucket_cursor, n, D);
    partition_kernel<<<(ne + 4095) / 4096, 256, 0, stream>>>(src, dst, ne, D, bucket_cursor, ebuf);
    csr_build_kernel<<<KBUCK, 256, 0, stream>>>(ebuf, row_ptr, n, D, csr_src);

    const int gemm_blocks = (n + 63) / 64;
    const int spmm_blocks = (n + 3) / 4;

    // --- layer 0: x1 = relu(norm_d*spmm(norm_s*(x@W0)) + spmm(x@R0) + b0) ---
    gemm_mfma<256><<<gemm_blocks, 256, 0, stream>>>(Xb, n, Wf0, norm_s, V);
    spmm_kernel<4, true, true><<<spmm_blocks, 256, 0, stream>>>(V, row_ptr, csr_src, norm_d, gc_b0, X1b, n);

    // --- layer 1 ---
    gemm_mfma<256><<<gemm_blocks, 256, 0, stream>>>(X1b, n, Wf1, norm_s, V);
    spmm_kernel<4, true, true><<<spmm_blocks, 256, 0, stream>>>(V, row_ptr, csr_src, norm_d, gc_b1, X1b, n);

    // --- layer 2: output 64-wide fp32, no relu ---
    gemm_mfma<128><<<gemm_blocks, 256, 0, stream>>>(X1b, n, Wf2, norm_s, V);
    spmm_kernel<2, false, false><<<spmm_blocks, 256, 0, stream>>>(V, row_ptr, csr_src, norm_d, gc_b2, out, n);
}

// Round 8
// 602.374 us; speedup vs baseline: 13.4963x; 1.1228x over previous
//
#include <hip/hip_runtime.h>
#include <cstdint>
#include <cstddef>

#define NFEAT 128
#define KBUCK 1024

typedef __attribute__((ext_vector_type(8))) short bf16x8;
typedef __attribute__((ext_vector_type(4))) float f32x4;

// bf16 <-> f32 helpers (RNE, no NaN handling needed — activations are finite)
__device__ __forceinline__ unsigned short f2bf(float x) {
    union { float f; unsigned u; } v; v.f = x;
    unsigned r = v.u + 0x7fffu + ((v.u >> 16) & 1u);
    return (unsigned short)(r >> 16);
}
__device__ __forceinline__ float bf2f(unsigned short b) {
    union { unsigned u; float f; } v; v.u = ((unsigned)b) << 16;
    return v.f;
}

// ---------------- preprocessing kernels ----------------

__global__ void zero_ints(int* __restrict__ p, int n) {
    int i = blockIdx.x * blockDim.x + threadIdx.x;
    if (i < n) p[i] = 0;
}

__global__ void cast_bf16_kernel(const float* __restrict__ x, unsigned short* __restrict__ y, int n4) {
    int i = blockIdx.x * blockDim.x + threadIdx.x;
    if (i < n4) {
        float4 v = ((const float4*)x)[i];
        ushort4 o;
        o.x = f2bf(v.x); o.y = f2bf(v.y); o.z = f2bf(v.z); o.w = f2bf(v.w);
        ((ushort4*)y)[i] = o;
    }
}

// Pack [gcW | resW] (fp32 row-major [128][SPLIT]) into bf16 MFMA B-fragment order:
// Wf[((kb*NT + nt)*64 + lane)*8 + j] = Wcat[kb*32 + (lane>>4)*8 + j][nt*16 + (lane&15)]
template <int NOUT>
__global__ void prep_wf(const float* __restrict__ gcW, const float* __restrict__ resW,
                        unsigned short* __restrict__ Wf) {
    constexpr int NT = NOUT / 16;
    constexpr int SPLIT = NOUT / 2;
    int tid = blockIdx.x * 256 + threadIdx.x;
    if (tid >= 128 * NOUT) return;
    int k = tid / NOUT, n = tid % NOUT;
    float v = (n < SPLIT) ? gcW[k * SPLIT + n] : resW[k * SPLIT + (n - SPLIT)];
    int kb = k >> 5, koff = k & 31, quad = koff >> 3, j = koff & 7;
    int nt = n >> 4, ncol = n & 15, lane = quad * 16 + ncol;
    Wf[((kb * NT + nt) * 64 + lane) * 8 + j] = f2bf(v);
}

// ---------------- fully-bucketed graph preprocessing ----------------
// Round-7 profile: degree_kernel 124 us, WRITE_SIZE 100 MB for 0.8 MB of counters —
// 3.2M random-address device atomics each dirtying a 64B line. Fix: no global atomics
// to random addresses anywhere. Bucket by node-range (KBUCK buckets, D nodes each);
// per-bucket blocks count/scan/build entirely in LDS with slice-local coalesced writes.

// Tile = 4096 edges. LDS double histogram -> per-(block,bucket) atomic into 1024-counter
// arrays (line-dense, cheap — proven by round-6 reserve step).
__global__ __launch_bounds__(256) void hist_kernel(
    const int* __restrict__ src, const int* __restrict__ dst, int ne, int D,
    int* __restrict__ dst_btot, int* __restrict__ src_btot) {
    __shared__ int hd[KBUCK], hs[KBUCK];
    const int t = threadIdx.x;
    const int tile0 = blockIdx.x * 4096;
    for (int i = t; i < KBUCK; i += 256) { hd[i] = 0; hs[i] = 0; }
    __syncthreads();
    #pragma unroll
    for (int j = 0; j < 16; j++) {
        int e = tile0 + j * 256 + t;
        if (e < ne) {
            atomicAdd(&hd[(unsigned)dst[e] / (unsigned)D], 1);
            atomicAdd(&hs[(unsigned)src[e] / (unsigned)D], 1);
        }
    }
    __syncthreads();
    for (int i = t; i < KBUCK; i += 256) {
        if (hd[i]) atomicAdd(&dst_btot[i], hd[i]);
        if (hs[i]) atomicAdd(&src_btot[i], hs[i]);
    }
}

// Single block of KBUCK threads: exclusive-scan both totals, init bases + cursors.
__global__ __launch_bounds__(KBUCK) void scan_buckets(
    const int* __restrict__ dst_btot, const int* __restrict__ src_btot,
    int* __restrict__ dst_base, int* __restrict__ src_base,
    int* __restrict__ dst_cursor, int* __restrict__ src_cursor,
    int* __restrict__ row_ptr, int n, int ne) {
    __shared__ int t1[KBUCK], t2[KBUCK];
    const int t = threadIdx.x;
    int v1 = dst_btot[t], v2 = src_btot[t];
    t1[t] = v1; t2[t] = v2;
    for (int off = 1; off < KBUCK; off <<= 1) {
        __syncthreads();
        int a = (t >= off) ? t1[t - off] : 0;
        int b = (t >= off) ? t2[t - off] : 0;
        __syncthreads();
        t1[t] += a; t2[t] += b;
    }
    __syncthreads();
    int e1 = t1[t] - v1, e2 = t2[t] - v2;
    dst_base[t] = e1; src_base[t] = e2;
    dst_cursor[t] = e1; src_cursor[t] = e2;
    if (t == KBUCK - 1) {
        dst_base[KBUCK] = t1[t];
        src_base[KBUCK] = t2[t];
        row_ptr[n] = ne;
    }
}

// Partition (src,dst) pairs bucket-contiguous by dst-range.
__global__ __launch_bounds__(256) void partition_dst(
    const int* __restrict__ src, const int* __restrict__ dst, int ne, int D,
    int* __restrict__ dst_cursor, uint2* __restrict__ ebuf) {
    __shared__ int hist[KBUCK];
    __shared__ int gbase[KBUCK];
    const int t = threadIdx.x;
    const int tile0 = blockIdx.x * 4096;

    for (int i = t; i < KBUCK; i += 256) hist[i] = 0;
    __syncthreads();

    int s[16], d[16], r[16];
    #pragma unroll
    for (int j = 0; j < 16; j++) {
        int e = tile0 + j * 256 + t;
        if (e < ne) {
            s[j] = src[e];
            d[j] = dst[e];
            int b = (int)((unsigned)d[j] / (unsigned)D);
            r[j] = atomicAdd(&hist[b], 1);
        }
    }
    __syncthreads();
    for (int i = t; i < KBUCK; i += 256) {
        int c = hist[i];
        gbase[i] = c ? atomicAdd(&dst_cursor[i], c) : 0;
    }
    __syncthreads();
    #pragma unroll
    for (int j = 0; j < 16; j++) {
        int e = tile0 + j * 256 + t;
        if (e < ne) {
            int b = (int)((unsigned)d[j] / (unsigned)D);
            ebuf[gbase[b] + r[j]] = make_uint2((unsigned)s[j], (unsigned)d[j]);
        }
    }
}

// Partition src values bucket-contiguous by src-range (for out-degree counting).
__global__ __launch_bounds__(256) void partition_src(
    const int* __restrict__ src, int ne, int D,
    int* __restrict__ src_cursor, unsigned* __restrict__ sbuf) {
    __shared__ int hist[KBUCK];
    __shared__ int gbase[KBUCK];
    const int t = threadIdx.x;
    const int tile0 = blockIdx.x * 4096;

    for (int i = t; i < KBUCK; i += 256) hist[i] = 0;
    __syncthreads();

    int s[16], r[16];
    #pragma unroll
    for (int j = 0; j < 16; j++) {
        int e = tile0 + j * 256 + t;
        if (e < ne) {
            s[j] = src[e];
            int b = (int)((unsigned)s[j] / (unsigned)D);
            r[j] = atomicAdd(&hist[b], 1);
        }
    }
    __syncthreads();
    for (int i = t; i < KBUCK; i += 256) {
        int c = hist[i];
        gbase[i] = c ? atomicAdd(&src_cursor[i], c) : 0;
    }
    __syncthreads();
    #pragma unroll
    for (int j = 0; j < 16; j++) {
        int e = tile0 + j * 256 + t;
        if (e < ne) {
            int b = (int)((unsigned)s[j] / (unsigned)D);
            sbuf[gbase[b] + r[j]] = (unsigned)s[j];
        }
    }
}

// One block per bucket: in-degree histogram (LDS), local scan -> row_ptr + norm_d,
// then rank-scatter csr_src. All global writes slice-local & coalesced. D <= 128.
__global__ __launch_bounds__(256) void build_dst(
    const uint2* __restrict__ ebuf, const int* __restrict__ dst_base,
    int n, int D, int* __restrict__ row_ptr, float* __restrict__ norm_d,
    int* __restrict__ csr_src) {
    __shared__ int cnt[128], sc[128], rp[128], rank[128];
    const int b = blockIdx.x;
    const int d_lo = b * D;
    if (d_lo >= n) return;
    const int d_hi = (d_lo + D < n) ? d_lo + D : n;
    const int e0 = dst_base[b], e1 = dst_base[b + 1];
    const int t = threadIdx.x;

    if (t < 128) { cnt[t] = 0; rank[t] = 0; }
    __syncthreads();
    for (int i = e0 + t; i < e1; i += 256)
        atomicAdd(&cnt[(int)ebuf[i].y - d_lo], 1);
    __syncthreads();
    if (t < 128) sc[t] = cnt[t];
    __syncthreads();
    for (int off = 1; off < 128; off <<= 1) {
        int v = (t < 128 && t >= off) ? sc[t - off] : 0;
        __syncthreads();
        if (t < 128) sc[t] += v;
        __syncthreads();
    }
    if (t < 128) {
        rp[t] = e0 + sc[t] - cnt[t];   // exclusive
        int d = d_lo + t;
        if (d < d_hi) {
            row_ptr[d] = rp[t];
            norm_d[d] = rsqrtf(fmaxf((float)cnt[t], 1.0f));
        }
    }
    __syncthreads();
    for (int i = e0 + t; i < e1; i += 256) {
        uint2 ed = ebuf[i];
        int dd = (int)ed.y - d_lo;
        int r = atomicAdd(&rank[dd], 1);
        csr_src[rp[dd] + r] = (int)ed.x;
    }
}

// One block per bucket: out-degree histogram -> norm_s.
__global__ __launch_bounds__(256) void build_src(
    const unsigned* __restrict__ sbuf, const int* __restrict__ src_base,
    int n, int D, float* __restrict__ norm_s) {
    __shared__ int cnt[128];
    const int b = blockIdx.x;
    const int d_lo = b * D;
    if (d_lo >= n) return;
    const int d_hi = (d_lo + D < n) ? d_lo + D : n;
    const int e0 = src_base[b], e1 = src_base[b + 1];
    const int t = threadIdx.x;
    if (t < 128) cnt[t] = 0;
    __syncthreads();
    for (int i = e0 + t; i < e1; i += 256)
        atomicAdd(&cnt[(int)sbuf[i] - d_lo], 1);
    __syncthreads();
    if (t < 128 && d_lo + t < d_hi)
        norm_s[d_lo + t] = rsqrtf(fmaxf((float)cnt[t], 1.0f));
}

// ---------------- MFMA dual-GEMM: V = X @ [gcW | resW], gc half scaled by norm_s[row] ----
// X: [M,128] bf16. Wf: fragment-major bf16 (see prep_wf). V: [M,NOUT] bf16.
// Block = 256 thr = 4 waves; wave w computes rows blockIdx.x*64 + w*16, all NOUT cols.
// mfma_f32_16x16x32_bf16 layouts (HW-verified m89/m91): A[m=lane&15][k=(lane>>4)*8+j],
// C/D col=lane&15, row=(lane>>4)*4+reg.

template <int NOUT>
__global__ __launch_bounds__(256) void gemm_mfma(
    const unsigned short* __restrict__ X, int M,
    const unsigned short* __restrict__ Wf,
    const float* __restrict__ norm_s, unsigned short* __restrict__ V) {
    constexpr int NT = NOUT / 16;
    constexpr int SPLIT = NOUT / 2;
    __shared__ unsigned short Bs[128 * NOUT];

    const int t = threadIdx.x;
    const int wave = t >> 6, lane = t & 63;
    const int r0 = blockIdx.x * 64 + wave * 16;

    // stage Wf -> LDS (contiguous 16B copies, conflict-free)
    constexpr int TOT16 = 128 * NOUT * 2 / 16;
    const uint4* gsrc = (const uint4*)Wf;
    uint4* ldst = (uint4*)Bs;
    for (int i = t; i < TOT16; i += 256) ldst[i] = gsrc[i];

    // A fragments from global (rows am = r0 + (lane&15), k = kb*32 + (lane>>4)*8 + j)
    const int am = r0 + (lane & 15);
    const int kq = (lane >> 4) * 8;
    bf16x8 afrag[4];
    if (am < M) {
        const unsigned short* ap = X + (size_t)am * NFEAT + kq;
        #pragma unroll
        for (int kb = 0; kb < 4; kb++)
            afrag[kb] = *(const bf16x8*)(ap + kb * 32);
    } else {
        #pragma unroll
        for (int kb = 0; kb < 4; kb++) afrag[kb] = bf16x8{};
    }

    // per-lane norm_s for the 4 output rows this lane owns (row = (lane>>4)*4 + reg)
    const int orow = r0 + (lane >> 4) * 4;
    float ns[4];
    #pragma unroll
    for (int r = 0; r < 4; r++)
        ns[r] = (orow + r < M) ? norm_s[orow + r] : 0.f;

    __syncthreads();

    #pragma unroll 1
    for (int nt = 0; nt < NT; nt++) {
        f32x4 acc = {0.f, 0.f, 0.f, 0.f};
        #pragma unroll
        for (int kb = 0; kb < 4; kb++) {
            bf16x8 b = *(const bf16x8*)(Bs + ((kb * NT + nt) * 64 + lane) * 8);
            acc = __builtin_amdgcn_mfma_f32_16x16x32_bf16(afrag[kb], b, acc, 0, 0, 0);
        }
        const int gcol = nt * 16 + (lane & 15);
        const bool isGc = gcol < SPLIT;
        #pragma unroll
        for (int r = 0; r < 4; r++) {
            int gm = orow + r;
            if (gm < M) {
                float v = acc[r] * (isGc ? ns[r] : 1.0f);
                V[(size_t)gm * NOUT + gcol] = f2bf(v);
            }
        }
    }
}

// ---------------- pull-mode SpMM + epilogue ----------------
// One wave per node. V row = 64*VEC bf16. Lanes 0..31 gc half, 32..63 residual half.
// Edge loop unrolled x4 with batched independent gathers (round-4: latency-bound fix).
// out[node] = relu? ( norm_d[node]*Agg_gc + Agg_res + bias ); fp32 accumulation.

template <int VEC, bool RELU, bool OUT_BF16>
__global__ __launch_bounds__(256) void spmm_kernel(
    const unsigned short* __restrict__ V, const int* __restrict__ row_ptr,
    const int* __restrict__ csr_src, const float* __restrict__ norm_d,
    const float* __restrict__ bias, void* __restrict__ outv, int n) {
    int wid = (blockIdx.x * 256 + threadIdx.x) >> 6;
    int lane = threadIdx.x & 63;
    if (wid >= n) return;

    constexpr int W = 64 * VEC;
    float acc[VEC];
    #pragma unroll
    for (int c = 0; c < VEC; c++) acc[c] = 0.f;

    const int e0 = row_ptr[wid];
    const int e1 = row_ptr[wid + 1];
    const unsigned short* Vl = V + (size_t)lane * VEC;

    int e = e0;
    if constexpr (VEC == 4) {
        for (; e + 4 <= e1; e += 4) {
            int s0 = csr_src[e];
            int s1 = csr_src[e + 1];
            int s2 = csr_src[e + 2];
            int s3 = csr_src[e + 3];
            ushort4 q0 = *(const ushort4*)(Vl + (size_t)s0 * W);
            ushort4 q1 = *(const ushort4*)(Vl + (size_t)s1 * W);
            ushort4 q2 = *(const ushort4*)(Vl + (size_t)s2 * W);
            ushort4 q3 = *(const ushort4*)(Vl + (size_t)s3 * W);
            acc[0] += (bf2f(q0.x) + bf2f(q1.x)) + (bf2f(q2.x) + bf2f(q3.x));
            acc[1] += (bf2f(q0.y) + bf2f(q1.y)) + (bf2f(q2.y) + bf2f(q3.y));
            acc[2] += (bf2f(q0.z) + bf2f(q1.z)) + (bf2f(q2.z) + bf2f(q3.z));
            acc[3] += (bf2f(q0.w) + bf2f(q1.w)) + (bf2f(q2.w) + bf2f(q3.w));
        }
        for (; e < e1; e++) {
            int s = csr_src[e];
            ushort4 q = *(const ushort4*)(Vl + (size_t)s * W);
            acc[0] += bf2f(q.x); acc[1] += bf2f(q.y);
            acc[2] += bf2f(q.z); acc[3] += bf2f(q.w);
        }
    } else {
        for (; e + 4 <= e1; e += 4) {
            int s0 = csr_src[e];
            int s1 = csr_src[e + 1];
            int s2 = csr_src[e + 2];
            int s3 = csr_src[e + 3];
            ushort2 q0 = *(const ushort2*)(Vl + (size_t)s0 * W);
            ushort2 q1 = *(const ushort2*)(Vl + (size_t)s1 * W);
            ushort2 q2 = *(const ushort2*)(Vl + (size_t)s2 * W);
            ushort2 q3 = *(const ushort2*)(Vl + (size_t)s3 * W);
            acc[0] += (bf2f(q0.x) + bf2f(q1.x)) + (bf2f(q2.x) + bf2f(q3.x));
            acc[1] += (bf2f(q0.y) + bf2f(q1.y)) + (bf2f(q2.y) + bf2f(q3.y));
        }
        for (; e < e1; e++) {
            int s = csr_src[e];
            ushort2 q = *(const ushort2*)(Vl + (size_t)s * W);
            acc[0] += bf2f(q.x); acc[1] += bf2f(q.y);
        }
    }

    float part[VEC];
    #pragma unroll
    for (int c = 0; c < VEC; c++) part[c] = __shfl(acc[c], (lane + 32) & 63, 64);

    if (lane < 32) {
        float nd = norm_d[wid];
        float res[VEC];
        #pragma unroll
        for (int c = 0; c < VEC; c++) {
            float r = nd * acc[c] + part[c] + bias[lane * VEC + c];
            if (RELU) r = fmaxf(r, 0.f);
            res[c] = r;
        }
        if constexpr (OUT_BF16) {
            unsigned short* po = (unsigned short*)outv + (size_t)wid * (32 * VEC) + lane * VEC;
            if constexpr (VEC == 4) {
                ushort4 o;
                o.x = f2bf(res[0]); o.y = f2bf(res[1]);
                o.z = f2bf(res[2]); o.w = f2bf(res[3]);
                *(ushort4*)po = o;
            } else {
                ushort2 o; o.x = f2bf(res[0]); o.y = f2bf(res[1]);
                *(ushort2*)po = o;
            }
        } else {
            float* po = (float*)outv + (size_t)wid * (32 * VEC) + lane * VEC;
            if constexpr (VEC == 4) {
                float4 o; o.x = res[0]; o.y = res[1]; o.z = res[2]; o.w = res[3];
                *(float4*)po = o;
            } else {
                float2 o; o.x = res[0]; o.y = res[1];
                *(float2*)po = o;
            }
        }
    }
}

// ---------------- launch ----------------

extern "C" void kernel_launch(void* const* d_in, const int* in_sizes, int n_in,
                              void* d_out, int out_size, void* d_ws, size_t ws_size,
                              hipStream_t stream) {
    const float* raw_x  = (const float*)d_in[0];
    const int*   src    = (const int*)d_in[1];
    const int*   dst    = (const int*)d_in[2];
    const float* gc_w0  = (const float*)d_in[3];
    const float* gc_b0  = (const float*)d_in[4];
    const float* gc_w1  = (const float*)d_in[5];
    const float* gc_b1  = (const float*)d_in[6];
    const float* gc_w2  = (const float*)d_in[7];
    const float* gc_b2  = (const float*)d_in[8];
    const float* res_w0 = (const float*)d_in[9];
    const float* res_w1 = (const float*)d_in[10];
    const float* res_w2 = (const float*)d_in[11];

    const int n  = in_sizes[0] / NFEAT;   // 100000
    const int ne = in_sizes[1];           // 1600000
    float* out = (float*)d_out;
    const int D = (n + KBUCK - 1) / KBUCK;   // nodes per bucket (98, <=128)

    // workspace layout
    char* w = (char*)d_ws;
    unsigned short* V   = (unsigned short*)w; w += (size_t)n * 256 * sizeof(unsigned short); // 51.2 MB
    unsigned short* Xb  = (unsigned short*)w; w += (size_t)n * 128 * sizeof(unsigned short); // 25.6 MB
    unsigned short* X1b = (unsigned short*)w; w += (size_t)n * 128 * sizeof(unsigned short); // 25.6 MB
    float* norm_s = (float*)w;   w += (size_t)n * sizeof(float);
    float* norm_d = (float*)w;   w += (size_t)n * sizeof(float);
    int* row_ptr = (int*)w;      w += (size_t)(n + 1) * sizeof(int);
    int* csr_src = (int*)w;      w += (size_t)ne * sizeof(int);        // 6.4 MB
    uint2* ebuf = (uint2*)w;     w += (size_t)ne * sizeof(uint2);      // 12.8 MB
    unsigned* sbuf = (unsigned*)w; w += (size_t)ne * sizeof(unsigned); // 6.4 MB
    int* dst_btot = (int*)w;     w += KBUCK * sizeof(int);
    int* src_btot = (int*)w;     w += KBUCK * sizeof(int);
    int* dst_base = (int*)w;     w += (KBUCK + 1) * sizeof(int);
    int* src_base = (int*)w;     w += (KBUCK + 1) * sizeof(int);
    int* dst_cursor = (int*)w;   w += KBUCK * sizeof(int);
    int* src_cursor = (int*)w;   w += KBUCK * sizeof(int);
    unsigned short* Wf0 = (unsigned short*)w; w += 128 * 256 * sizeof(unsigned short);
    unsigned short* Wf1 = (unsigned short*)w; w += 128 * 256 * sizeof(unsigned short);
    unsigned short* Wf2 = (unsigned short*)w; w += 128 * 128 * sizeof(unsigned short);

    const int tiles = (ne + 4095) / 4096;

    // --- preprocessing: bf16 cast, weight fragments, bucketed CSR + degrees ---
    cast_bf16_kernel<<<(n * (NFEAT / 4) + 255) / 256, 256, 0, stream>>>(raw_x, Xb, n * (NFEAT / 4));
    prep_wf<256><<<128, 256, 0, stream>>>(gc_w0, res_w0, Wf0);
    prep_wf<256><<<128, 256, 0, stream>>>(gc_w1, res_w1, Wf1);
    prep_wf<128><<<64, 256, 0, stream>>>(gc_w2, res_w2, Wf2);
    zero_ints<<<(2 * KBUCK + 255) / 256, 256, 0, stream>>>(dst_btot, 2 * KBUCK); // dst_btot+src_btot contiguous
    hist_kernel<<<tiles, 256, 0, stream>>>(src, dst, ne, D, dst_btot, src_btot);
    scan_buckets<<<1, KBUCK, 0, stream>>>(dst_btot, src_btot, dst_base, src_base,
                                          dst_cursor, src_cursor, row_ptr, n, ne);
    partition_dst<<<tiles, 256, 0, stream>>>(src, dst, ne, D, dst_cursor, ebuf);
    partition_src<<<tiles, 256, 0, stream>>>(src, ne, D, src_cursor, sbuf);
    build_dst<<<KBUCK, 256, 0, stream>>>(ebuf, dst_base, n, D, row_ptr, norm_d, csr_src);
    build_src<<<KBUCK, 256, 0, stream>>>(sbuf, src_base, n, D, norm_s);

    const int gemm_blocks = (n + 63) / 64;
    const int spmm_blocks = (n + 3) / 4;

    // --- layer 0: x1 = relu(norm_d*spmm(norm_s*(x@W0)) + spmm(x@R0) + b0) ---
    gemm_mfma<256><<<gemm_blocks, 256, 0, stream>>>(Xb, n, Wf0, norm_s, V);
    spmm_kernel<4, true, true><<<spmm_blocks, 256, 0, stream>>>(V, row_ptr, csr_src, norm_d, gc_b0, X1b, n);

    // --- layer 1 ---
    gemm_mfma<256><<<gemm_blocks, 256, 0, stream>>>(X1b, n, Wf1, norm_s, V);
    spmm_kernel<4, true, true><<<spmm_blocks, 256, 0, stream>>>(V, row_ptr, csr_src, norm_d, gc_b1, X1b, n);

    // --- layer 2: output 64-wide fp32, no relu ---
    gemm_mfma<128><<<gemm_blocks, 256, 0, stream>>>(X1b, n, Wf2, norm_s, V);
    spmm_kernel<2, false, false><<<spmm_blocks, 256, 0, stream>>>(V, row_ptr, csr_src, norm_d, gc_b2, out, n);
}

// Round 9
// 563.720 us; speedup vs baseline: 14.4218x; 1.0686x over previous
//
#include <hip/hip_runtime.h>
#include <cstdint>
#include <cstddef>

#define NFEAT 128
#define KBUCK 1024

typedef __attribute__((ext_vector_type(8))) short bf16x8;
typedef __attribute__((ext_vector_type(4))) float f32x4;

// bf16 <-> f32 helpers (RNE, no NaN handling needed — activations are finite)
__device__ __forceinline__ unsigned short f2bf(float x) {
    union { float f; unsigned u; } v; v.f = x;
    unsigned r = v.u + 0x7fffu + ((v.u >> 16) & 1u);
    return (unsigned short)(r >> 16);
}
__device__ __forceinline__ float bf2f(unsigned short b) {
    union { unsigned u; float f; } v; v.u = ((unsigned)b) << 16;
    return v.f;
}

// ---------------- preprocessing kernels ----------------

__global__ void zero_ints(int* __restrict__ p, int n) {
    int i = blockIdx.x * blockDim.x + threadIdx.x;
    if (i < n) p[i] = 0;
}

__global__ void cast_bf16_kernel(const float* __restrict__ x, unsigned short* __restrict__ y, int n4) {
    int i = blockIdx.x * blockDim.x + threadIdx.x;
    if (i < n4) {
        float4 v = ((const float4*)x)[i];
        ushort4 o;
        o.x = f2bf(v.x); o.y = f2bf(v.y); o.z = f2bf(v.z); o.w = f2bf(v.w);
        ((ushort4*)y)[i] = o;
    }
}

// Pack Wcat (256 x NCOL: rows 0..127 = gcW, 128..255 = resW; fp32) into bf16 MFMA
// B-fragment order for K=256 GEMM:
// Wf[((kb*NT + nt)*64 + lane)*8 + j] = Wcat[kb*32 + (lane>>4)*8 + j][nt*16 + (lane&15)]
template <int NCOL>
__global__ void prep_wf2(const float* __restrict__ gcW, const float* __restrict__ resW,
                         unsigned short* __restrict__ Wf) {
    constexpr int NT = NCOL / 16;
    int tid = blockIdx.x * 256 + threadIdx.x;
    if (tid >= 256 * NCOL) return;
    int k = tid / NCOL, c = tid % NCOL;
    float v = (k < 128) ? gcW[k * NCOL + c] : resW[(k - 128) * NCOL + c];
    int kb = k >> 5, koff = k & 31, quad = koff >> 3, j = koff & 7;
    int nt = c >> 4, ncol = c & 15, lane = quad * 16 + ncol;
    Wf[((kb * NT + nt) * 64 + lane) * 8 + j] = f2bf(v);
}

// ---------------- fully-bucketed graph preprocessing (rounds 6-7) ----------------
// No global atomics to random addresses anywhere: bucket by node-range, per-bucket
// blocks count/scan/build in LDS with slice-local coalesced writes.

__global__ __launch_bounds__(256) void hist_kernel(
    const int* __restrict__ src, const int* __restrict__ dst, int ne, int D,
    int* __restrict__ dst_btot, int* __restrict__ src_btot) {
    __shared__ int hd[KBUCK], hs[KBUCK];
    const int t = threadIdx.x;
    const int tile0 = blockIdx.x * 4096;
    for (int i = t; i < KBUCK; i += 256) { hd[i] = 0; hs[i] = 0; }
    __syncthreads();
    #pragma unroll
    for (int j = 0; j < 16; j++) {
        int e = tile0 + j * 256 + t;
        if (e < ne) {
            atomicAdd(&hd[(unsigned)dst[e] / (unsigned)D], 1);
            atomicAdd(&hs[(unsigned)src[e] / (unsigned)D], 1);
        }
    }
    __syncthreads();
    for (int i = t; i < KBUCK; i += 256) {
        if (hd[i]) atomicAdd(&dst_btot[i], hd[i]);
        if (hs[i]) atomicAdd(&src_btot[i], hs[i]);
    }
}

__global__ __launch_bounds__(KBUCK) void scan_buckets(
    const int* __restrict__ dst_btot, const int* __restrict__ src_btot,
    int* __restrict__ dst_base, int* __restrict__ src_base,
    int* __restrict__ dst_cursor, int* __restrict__ src_cursor,
    int* __restrict__ row_ptr, int n, int ne) {
    __shared__ int t1[KBUCK], t2[KBUCK];
    const int t = threadIdx.x;
    int v1 = dst_btot[t], v2 = src_btot[t];
    t1[t] = v1; t2[t] = v2;
    for (int off = 1; off < KBUCK; off <<= 1) {
        __syncthreads();
        int a = (t >= off) ? t1[t - off] : 0;
        int b = (t >= off) ? t2[t - off] : 0;
        __syncthreads();
        t1[t] += a; t2[t] += b;
    }
    __syncthreads();
    int e1 = t1[t] - v1, e2 = t2[t] - v2;
    dst_base[t] = e1; src_base[t] = e2;
    dst_cursor[t] = e1; src_cursor[t] = e2;
    if (t == KBUCK - 1) {
        dst_base[KBUCK] = t1[t];
        src_base[KBUCK] = t2[t];
        row_ptr[n] = ne;
    }
}

__global__ __launch_bounds__(256) void partition_dst(
    const int* __restrict__ src, const int* __restrict__ dst, int ne, int D,
    int* __restrict__ dst_cursor, uint2* __restrict__ ebuf) {
    __shared__ int hist[KBUCK];
    __shared__ int gbase[KBUCK];
    const int t = threadIdx.x;
    const int tile0 = blockIdx.x * 4096;

    for (int i = t; i < KBUCK; i += 256) hist[i] = 0;
    __syncthreads();

    int s[16], d[16], r[16];
    #pragma unroll
    for (int j = 0; j < 16; j++) {
        int e = tile0 + j * 256 + t;
        if (e < ne) {
            s[j] = src[e];
            d[j] = dst[e];
            int b = (int)((unsigned)d[j] / (unsigned)D);
            r[j] = atomicAdd(&hist[b], 1);
        }
    }
    __syncthreads();
    for (int i = t; i < KBUCK; i += 256) {
        int c = hist[i];
        gbase[i] = c ? atomicAdd(&dst_cursor[i], c) : 0;
    }
    __syncthreads();
    #pragma unroll
    for (int j = 0; j < 16; j++) {
        int e = tile0 + j * 256 + t;
        if (e < ne) {
            int b = (int)((unsigned)d[j] / (unsigned)D);
            ebuf[gbase[b] + r[j]] = make_uint2((unsigned)s[j], (unsigned)d[j]);
        }
    }
}

__global__ __launch_bounds__(256) void partition_src(
    const int* __restrict__ src, int ne, int D,
    int* __restrict__ src_cursor, unsigned* __restrict__ sbuf) {
    __shared__ int hist[KBUCK];
    __shared__ int gbase[KBUCK];
    const int t = threadIdx.x;
    const int tile0 = blockIdx.x * 4096;

    for (int i = t; i < KBUCK; i += 256) hist[i] = 0;
    __syncthreads();

    int s[16], r[16];
    #pragma unroll
    for (int j = 0; j < 16; j++) {
        int e = tile0 + j * 256 + t;
        if (e < ne) {
            s[j] = src[e];
            int b = (int)((unsigned)s[j] / (unsigned)D);
            r[j] = atomicAdd(&hist[b], 1);
        }
    }
    __syncthreads();
    for (int i = t; i < KBUCK; i += 256) {
        int c = hist[i];
        gbase[i] = c ? atomicAdd(&src_cursor[i], c) : 0;
    }
    __syncthreads();
    #pragma unroll
    for (int j = 0; j < 16; j++) {
        int e = tile0 + j * 256 + t;
        if (e < ne) {
            int b = (int)((unsigned)s[j] / (unsigned)D);
            sbuf[gbase[b] + r[j]] = (unsigned)s[j];
        }
    }
}

__global__ __launch_bounds__(256) void build_dst(
    const uint2* __restrict__ ebuf, const int* __restrict__ dst_base,
    int n, int D, int* __restrict__ row_ptr, float* __restrict__ norm_d,
    int* __restrict__ csr_src) {
    __shared__ int cnt[128], sc[128], rp[128], rank[128];
    const int b = blockIdx.x;
    const int d_lo = b * D;
    if (d_lo >= n) return;
    const int d_hi = (d_lo + D < n) ? d_lo + D : n;
    const int e0 = dst_base[b], e1 = dst_base[b + 1];
    const int t = threadIdx.x;

    if (t < 128) { cnt[t] = 0; rank[t] = 0; }
    __syncthreads();
    for (int i = e0 + t; i < e1; i += 256)
        atomicAdd(&cnt[(int)ebuf[i].y - d_lo], 1);
    __syncthreads();
    if (t < 128) sc[t] = cnt[t];
    __syncthreads();
    for (int off = 1; off < 128; off <<= 1) {
        int v = (t < 128 && t >= off) ? sc[t - off] : 0;
        __syncthreads();
        if (t < 128) sc[t] += v;
        __syncthreads();
    }
    if (t < 128) {
        rp[t] = e0 + sc[t] - cnt[t];   // exclusive
        int d = d_lo + t;
        if (d < d_hi) {
            row_ptr[d] = rp[t];
            norm_d[d] = rsqrtf(fmaxf((float)cnt[t], 1.0f));
        }
    }
    __syncthreads();
    for (int i = e0 + t; i < e1; i += 256) {
        uint2 ed = ebuf[i];
        int dd = (int)ed.y - d_lo;
        int r = atomicAdd(&rank[dd], 1);
        csr_src[rp[dd] + r] = (int)ed.x;
    }
}

__global__ __launch_bounds__(256) void build_src(
    const unsigned* __restrict__ sbuf, const int* __restrict__ src_base,
    int n, int D, float* __restrict__ norm_s) {
    __shared__ int cnt[128];
    const int b = blockIdx.x;
    const int d_lo = b * D;
    if (d_lo >= n) return;
    const int d_hi = (d_lo + D < n) ? d_lo + D : n;
    const int e0 = src_base[b], e1 = src_base[b + 1];
    const int t = threadIdx.x;
    if (t < 128) cnt[t] = 0;
    __syncthreads();
    for (int i = e0 + t; i < e1; i += 256)
        atomicAdd(&cnt[(int)sbuf[i] - d_lo], 1);
    __syncthreads();
    if (t < 128 && d_lo + t < d_hi)
        norm_s[d_lo + t] = rsqrtf(fmaxf((float)cnt[t], 1.0f));
}

// ---------------- aggregate-first SpMM: U = [norm_d .* (A@(norm_s.*x)) | A@x] ----------------
// Round-8 insight: spmm and the dense projection commute (A@(xW) = (A@x)W), so gather
// the 128-wide INPUT rows (256 B) instead of 256-wide post-GEMM rows (512 B): halves
// gather bytes AND halves the gathered working set (25.6 vs 51.2 MB). Two fp32
// accumulators per lane-column: plain and norm_s-scaled. One wave per node; lane holds
// cols [2*lane, 2*lane+1]. Edge loop unrolled x8 for MLP (round-4 lesson, smaller granules).

__global__ __launch_bounds__(256) void spmm_pre(
    const unsigned short* __restrict__ X, const int* __restrict__ row_ptr,
    const int* __restrict__ csr_src, const float* __restrict__ norm_s,
    const float* __restrict__ norm_d, unsigned short* __restrict__ U, int n) {
    int wid = (blockIdx.x * 256 + threadIdx.x) >> 6;
    int lane = threadIdx.x & 63;
    if (wid >= n) return;

    float ap0 = 0.f, ap1 = 0.f, as0 = 0.f, as1 = 0.f;
    const int e0 = row_ptr[wid];
    const int e1 = row_ptr[wid + 1];
    const unsigned short* Xl = X + lane * 2;

    int e = e0;
    for (; e + 8 <= e1; e += 8) {
        int s[8]; ushort2 q[8]; float wv[8];
        #pragma unroll
        for (int i = 0; i < 8; i++) s[i] = csr_src[e + i];
        #pragma unroll
        for (int i = 0; i < 8; i++) q[i] = *(const ushort2*)(Xl + (size_t)s[i] * NFEAT);
        #pragma unroll
        for (int i = 0; i < 8; i++) wv[i] = norm_s[s[i]];
        #pragma unroll
        for (int i = 0; i < 8; i++) {
            float x0 = bf2f(q[i].x), x1 = bf2f(q[i].y);
            ap0 += x0; ap1 += x1;
            as0 = fmaf(wv[i], x0, as0); as1 = fmaf(wv[i], x1, as1);
        }
    }
    for (; e < e1; e++) {
        int s = csr_src[e];
        ushort2 q = *(const ushort2*)(Xl + (size_t)s * NFEAT);
        float wv = norm_s[s];
        float x0 = bf2f(q.x), x1 = bf2f(q.y);
        ap0 += x0; ap1 += x1;
        as0 = fmaf(wv, x0, as0); as1 = fmaf(wv, x1, as1);
    }

    float nd = norm_d[wid];
    ushort2 gc, rs;
    gc.x = f2bf(nd * as0); gc.y = f2bf(nd * as1);
    rs.x = f2bf(ap0);      rs.y = f2bf(ap1);
    unsigned short* Ur = U + (size_t)wid * 256;
    *(ushort2*)(Ur + lane * 2) = gc;
    *(ushort2*)(Ur + 128 + lane * 2) = rs;
}

// ---------------- MFMA GEMM: y = U @ [W;R] + b (+relu), K=256 ----------------
// U: [M,256] bf16. Wf: fragment-major bf16 (prep_wf2). Block = 4 waves; wave w does
// rows blockIdx.x*64 + w*16, all NCOL cols. A (16x256) = 8 bf16x8 frags in registers.
// mfma_f32_16x16x32_bf16 layouts (HW-verified m89/m91): A[m=lane&15][k=(lane>>4)*8+j],
// C/D col=lane&15, row=(lane>>4)*4+reg.

template <int NCOL, bool RELU, bool OUT_BF16>
__global__ __launch_bounds__(256) void gemm_mfma(
    const unsigned short* __restrict__ U, int M,
    const unsigned short* __restrict__ Wf,
    const float* __restrict__ bias, void* __restrict__ outv) {
    constexpr int NT = NCOL / 16;
    __shared__ unsigned short Bs[256 * NCOL];

    const int t = threadIdx.x;
    const int wave = t >> 6, lane = t & 63;
    const int r0 = blockIdx.x * 64 + wave * 16;

    // stage Wf -> LDS (contiguous 16B copies, conflict-free)
    constexpr int TOT16 = 256 * NCOL * 2 / 16;
    const uint4* gsrc = (const uint4*)Wf;
    uint4* ldst = (uint4*)Bs;
    for (int i = t; i < TOT16; i += 256) ldst[i] = gsrc[i];

    // A fragments (rows am = r0 + (lane&15), k = kb*32 + (lane>>4)*8 + j)
    const int am = r0 + (lane & 15);
    const int kq = (lane >> 4) * 8;
    bf16x8 afrag[8];
    if (am < M) {
        const unsigned short* ap = U + (size_t)am * 256 + kq;
        #pragma unroll
        for (int kb = 0; kb < 8; kb++)
            afrag[kb] = *(const bf16x8*)(ap + kb * 32);
    } else {
        #pragma unroll
        for (int kb = 0; kb < 8; kb++) afrag[kb] = bf16x8{};
    }

    const int orow = r0 + (lane >> 4) * 4;
    __syncthreads();

    #pragma unroll 1
    for (int nt = 0; nt < NT; nt++) {
        f32x4 acc = {0.f, 0.f, 0.f, 0.f};
        #pragma unroll
        for (int kb = 0; kb < 8; kb++) {
            bf16x8 b = *(const bf16x8*)(Bs + ((kb * NT + nt) * 64 + lane) * 8);
            acc = __builtin_amdgcn_mfma_f32_16x16x32_bf16(afrag[kb], b, acc, 0, 0, 0);
        }
        const int gcol = nt * 16 + (lane & 15);
        const float bv = bias[gcol];
        #pragma unroll
        for (int r = 0; r < 4; r++) {
            int gm = orow + r;
            if (gm < M) {
                float v = acc[r] + bv;
                if (RELU) v = fmaxf(v, 0.f);
                if constexpr (OUT_BF16)
                    ((unsigned short*)outv)[(size_t)gm * NCOL + gcol] = f2bf(v);
                else
                    ((float*)outv)[(size_t)gm * NCOL + gcol] = v;
            }
        }
    }
}

// ---------------- launch ----------------

extern "C" void kernel_launch(void* const* d_in, const int* in_sizes, int n_in,
                              void* d_out, int out_size, void* d_ws, size_t ws_size,
                              hipStream_t stream) {
    const float* raw_x  = (const float*)d_in[0];
    const int*   src    = (const int*)d_in[1];
    const int*   dst    = (const int*)d_in[2];
    const float* gc_w0  = (const float*)d_in[3];
    const float* gc_b0  = (const float*)d_in[4];
    const float* gc_w1  = (const float*)d_in[5];
    const float* gc_b1  = (const float*)d_in[6];
    const float* gc_w2  = (const float*)d_in[7];
    const float* gc_b2  = (const float*)d_in[8];
    const float* res_w0 = (const float*)d_in[9];
    const float* res_w1 = (const float*)d_in[10];
    const float* res_w2 = (const float*)d_in[11];

    const int n  = in_sizes[0] / NFEAT;   // 100000
    const int ne = in_sizes[1];           // 1600000
    float* out = (float*)d_out;
    const int D = (n + KBUCK - 1) / KBUCK;   // nodes per bucket (98, <=128)

    // workspace layout
    char* w = (char*)d_ws;
    unsigned short* U   = (unsigned short*)w; w += (size_t)n * 256 * sizeof(unsigned short); // 51.2 MB
    unsigned short* Xb  = (unsigned short*)w; w += (size_t)n * 128 * sizeof(unsigned short); // 25.6 MB
    unsigned short* X1b = (unsigned short*)w; w += (size_t)n * 128 * sizeof(unsigned short); // 25.6 MB
    float* norm_s = (float*)w;   w += (size_t)n * sizeof(float);
    float* norm_d = (float*)w;   w += (size_t)n * sizeof(float);
    int* row_ptr = (int*)w;      w += (size_t)(n + 1) * sizeof(int);
    int* csr_src = (int*)w;      w += (size_t)ne * sizeof(int);        // 6.4 MB
    uint2* ebuf = (uint2*)w;     w += (size_t)ne * sizeof(uint2);      // 12.8 MB
    unsigned* sbuf = (unsigned*)w; w += (size_t)ne * sizeof(unsigned); // 6.4 MB
    int* dst_btot = (int*)w;     w += KBUCK * sizeof(int);
    int* src_btot = (int*)w;     w += KBUCK * sizeof(int);
    int* dst_base = (int*)w;     w += (KBUCK + 1) * sizeof(int);
    int* src_base = (int*)w;     w += (KBUCK + 1) * sizeof(int);
    int* dst_cursor = (int*)w;   w += KBUCK * sizeof(int);
    int* src_cursor = (int*)w;   w += KBUCK * sizeof(int);
    unsigned short* Wf0 = (unsigned short*)w; w += 256 * 128 * sizeof(unsigned short);
    unsigned short* Wf1 = (unsigned short*)w; w += 256 * 128 * sizeof(unsigned short);
    unsigned short* Wf2 = (unsigned short*)w; w += 256 * 64 * sizeof(unsigned short);

    const int tiles = (ne + 4095) / 4096;

    // --- preprocessing: bf16 cast, weight fragments, bucketed CSR + degrees ---
    cast_bf16_kernel<<<(n * (NFEAT / 4) + 255) / 256, 256, 0, stream>>>(raw_x, Xb, n * (NFEAT / 4));
    prep_wf2<128><<<128, 256, 0, stream>>>(gc_w0, res_w0, Wf0);
    prep_wf2<128><<<128, 256, 0, stream>>>(gc_w1, res_w1, Wf1);
    prep_wf2<64><<<64, 256, 0, stream>>>(gc_w2, res_w2, Wf2);
    zero_ints<<<(2 * KBUCK + 255) / 256, 256, 0, stream>>>(dst_btot, 2 * KBUCK); // dst_btot+src_btot contiguous
    hist_kernel<<<tiles, 256, 0, stream>>>(src, dst, ne, D, dst_btot, src_btot);
    scan_buckets<<<1, KBUCK, 0, stream>>>(dst_btot, src_btot, dst_base, src_base,
                                          dst_cursor, src_cursor, row_ptr, n, ne);
    partition_dst<<<tiles, 256, 0, stream>>>(src, dst, ne, D, dst_cursor, ebuf);
    partition_src<<<tiles, 256, 0, stream>>>(src, ne, D, src_cursor, sbuf);
    build_dst<<<KBUCK, 256, 0, stream>>>(ebuf, dst_base, n, D, row_ptr, norm_d, csr_src);
    build_src<<<KBUCK, 256, 0, stream>>>(sbuf, src_base, n, D, norm_s);

    const int gemm_blocks = (n + 63) / 64;
    const int spmm_blocks = (n + 3) / 4;

    // --- layer 0: x1 = relu([nd*A(ns*x) | A x] @ [W0;R0] + b0) ---
    spmm_pre<<<spmm_blocks, 256, 0, stream>>>(Xb, row_ptr, csr_src, norm_s, norm_d, U, n);
    gemm_mfma<128, true, true><<<gemm_blocks, 256, 0, stream>>>(U, n, Wf0, gc_b0, X1b);

    // --- layer 1 ---
    spmm_pre<<<spmm_blocks, 256, 0, stream>>>(X1b, row_ptr, csr_src, norm_s, norm_d, U, n);
    gemm_mfma<128, true, true><<<gemm_blocks, 256, 0, stream>>>(U, n, Wf1, gc_b1, X1b);

    // --- layer 2: output 64-wide fp32, no relu ---
    spmm_pre<<<spmm_blocks, 256, 0, stream>>>(X1b, row_ptr, csr_src, norm_s, norm_d, U, n);
    gemm_mfma<64, false, false><<<gemm_blocks, 256, 0, stream>>>(U, n, Wf2, gc_b2, out);
}